// Round 5
// baseline (654.819 us; speedup 1.0000x reference)
//
#include <hip/hip_runtime.h>

#define NB 16
#define NS 1024
#define NHID 64
#define NHEADS 4
#define NDH 16
#define LN_EPS 1e-5f

// ---------------------------------------------------------------------------
// Kernel 1: QKV projection (unchanged).
// ---------------------------------------------------------------------------
__global__ __launch_bounds__(256) void qkv_kernel(
    const float* __restrict__ x,
    const float* __restrict__ Wq, const float* __restrict__ bq,
    const float* __restrict__ Wk, const float* __restrict__ bk,
    const float* __restrict__ Wv, const float* __restrict__ bv,
    float* __restrict__ qo, float* __restrict__ ko, float* __restrict__ vo)
{
    __shared__ float wqt[64][65], wkt[64][65], wvt[64][65];
    __shared__ float xs[32][64];
    int t = threadIdx.x;
    int row0 = blockIdx.x * 32;
    for (int i = t; i < 4096; i += 256) {
        int c = i >> 6, j = i & 63;
        wqt[j][c] = Wq[i];
        wkt[j][c] = Wk[i];
        wvt[j][c] = Wv[i];
    }
    for (int i = t; i < 2048; i += 256) {
        xs[i >> 6][i & 63] = x[(size_t)row0 * 64 + i];
    }
    __syncthreads();
    int c = t & 63, rq = t >> 6;
    int h = c >> 4, d = c & 15;
    float bqv = bq[c], bkv = bk[c], bvv = bv[c];
    for (int rr = 0; rr < 8; ++rr) {
        int r = rq * 8 + rr;
        float aq = bqv, ak = bkv, av = bvv;
        #pragma unroll
        for (int j = 0; j < 64; ++j) {
            float xv = xs[r][j];
            aq = fmaf(xv, wqt[j][c], aq);
            ak = fmaf(xv, wkt[j][c], ak);
            av = fmaf(xv, wvt[j][c], av);
        }
        int srow = row0 + r;
        int b_ = srow >> 10, s_ = srow & 1023;
        size_t o = (((size_t)(b_ * NHEADS + h)) * NS + s_) * NDH + d;
        qo[o] = aq; ko[o] = ak; vo[o] = av;
    }
}

// ---------------------------------------------------------------------------
// Kernel 2 (attn4): round-3 structure + uniform work via causal pairing.
// Block = (b, pair p): processes q-tile p (16 rows) then q-tile 63-p
// -> every block does ~16.5 K-tile-units/pass (no straggler blocks).
// Lane: hp = ln>>5 (head pair), kx = (ln>>4)&1 (k-split, reduced by shfl 16),
// ql = ln&15 (q row). Wave wv owns k's [wv*16, wv*16+16) of each 64-k tile.
// Register shape identical to round-3 (116 VGPR, no spill): qv[2][4], o4[2][4].
// LDS 40 KB (obuf aliases K/V pool) -> 3 blocks/CU = 12 waves/CU sustained.
// ---------------------------------------------------------------------------
__global__ __launch_bounds__(256, 3) void attn4_kernel(
    const float* __restrict__ q, const float* __restrict__ k,
    const float* __restrict__ v, const int* __restrict__ lengths,
    float* __restrict__ amean,   // [B,S,S]
    float* __restrict__ out)     // [B,S,64]
{
    __shared__ float pool[2 * 64 * 68];      // Klds | Vlds ; obuf aliases Klds
    float (*Klds)[68] = (float(*)[68])pool;
    float (*Vlds)[68] = (float(*)[68])(pool + 64 * 68);
    __shared__ float alds[16][65];
    __shared__ float zlds[4][32][2];

    const int t  = threadIdx.x;
    const int wv = t >> 6, ln = t & 63;
    const int hp = ln >> 5;
    const int kx = (ln >> 4) & 1;
    const int ql = ln & 15;
    const int b  = blockIdx.x & 15;          // interleave batches across CUs
    const int pr = blockIdx.x >> 4;          // 0..31
    const int len = lengths[b];

    for (int half = 0; half < 2; ++half) {
        const int qt = half ? (63 - pr) : pr;
        const int q0 = qt << 4;
        const int qrow = q0 + ql;
        const bool qvalid = qrow < len;

        // Q rows -> registers (heads 2hp, 2hp+1)
        float4 qv[2][4];
        #pragma unroll
        for (int e = 0; e < 2; ++e) {
            const float4* qp = (const float4*)
                &q[(((size_t)(b * NHEADS + hp * 2 + e)) * NS + qrow) * NDH];
            qv[e][0] = qp[0]; qv[e][1] = qp[1]; qv[e][2] = qp[2]; qv[e][3] = qp[3];
        }

        const int nk = (len <= q0) ? 0 : min(q0 + 16, len);
        const int ntiles = (nk + 63) >> 6;

        // ---------------- pass 1: Z ----------------
        float Z0 = 0.f, Z1 = 0.f;
        for (int tile = 0; tile < ntiles; ++tile) {
            const int k0 = tile << 6;
            #pragma unroll
            for (int i = 0; i < 4; ++i) {
                int idx = t + 256 * i, kk = idx & 63, j4 = idx >> 6;
                *(float4*)&Klds[kk][j4 * 4] = *(const float4*)
                    &k[(((size_t)(b * NHEADS + (j4 >> 2))) * NS + k0 + kk) * NDH + (j4 & 3) * 4];
            }
            __syncthreads();
            #pragma unroll
            for (int kki = 0; kki < 8; ++kki) {
                const int kk = (wv << 4) + (kki << 1) + kx, kg = k0 + kk;
                const float4* rk = (const float4*)&Klds[kk][hp * 32];
                float s0 = 0.f, s1 = 0.f;
                #pragma unroll
                for (int i = 0; i < 4; ++i) {
                    float4 ka = rk[i], kb2 = rk[4 + i];
                    s0 = fmaf(ka.x, qv[0][i].x, s0); s0 = fmaf(ka.y, qv[0][i].y, s0);
                    s0 = fmaf(ka.z, qv[0][i].z, s0); s0 = fmaf(ka.w, qv[0][i].w, s0);
                    s1 = fmaf(kb2.x, qv[1][i].x, s1); s1 = fmaf(kb2.y, qv[1][i].y, s1);
                    s1 = fmaf(kb2.z, qv[1][i].z, s1); s1 = fmaf(kb2.w, qv[1][i].w, s1);
                }
                const bool valid = qvalid && (kg <= qrow);
                Z0 += valid ? __expf(s0 * 0.125f) : 0.f;
                Z1 += valid ? __expf(s1 * 0.125f) : 0.f;
            }
            __syncthreads();
        }
        Z0 += __shfl_xor(Z0, 16, 64);
        Z1 += __shfl_xor(Z1, 16, 64);
        if (kx == 0) {
            zlds[wv][hp * 16 + ql][0] = Z0;
            zlds[wv][hp * 16 + ql][1] = Z1;
        }
        __syncthreads();
        const int zi = hp * 16 + ql;
        const float zt0 = zlds[0][zi][0] + zlds[1][zi][0] + zlds[2][zi][0] + zlds[3][zi][0];
        const float zt1 = zlds[0][zi][1] + zlds[1][zi][1] + zlds[2][zi][1] + zlds[3][zi][1];
        const float iz0 = (zt0 > 0.f) ? 1.f / zt0 : 0.f;
        const float iz1 = (zt1 > 0.f) ? 1.f / zt1 : 0.f;
        __syncthreads();

        // ---------------- pass 2: probs, amean, PV ----------------
        float4 o4[2][4];
        #pragma unroll
        for (int e = 0; e < 2; ++e)
            #pragma unroll
            for (int i = 0; i < 4; ++i) o4[e][i] = make_float4(0.f, 0.f, 0.f, 0.f);

        for (int tile = 0; tile < ntiles; ++tile) {
            const int k0 = tile << 6;
            if (tile > 0) {                       // flush previous amean tile
                const int kp = k0 - 64;
                int r = t >> 4, c4 = t & 15;
                float4 w4 = make_float4(alds[r][c4 * 4], alds[r][c4 * 4 + 1],
                                        alds[r][c4 * 4 + 2], alds[r][c4 * 4 + 3]);
                *(float4*)&amean[((size_t)(b * NS + q0 + r)) * NS + kp + c4 * 4] = w4;
            }
            #pragma unroll
            for (int i = 0; i < 4; ++i) {
                int idx = t + 256 * i, kk = idx & 63, j4 = idx >> 6;
                size_t goff = (((size_t)(b * NHEADS + (j4 >> 2))) * NS + k0 + kk) * NDH + (j4 & 3) * 4;
                *(float4*)&Klds[kk][j4 * 4] = *(const float4*)&k[goff];
                *(float4*)&Vlds[kk][j4 * 4] = *(const float4*)&v[goff];
            }
            __syncthreads();
            #pragma unroll
            for (int kki = 0; kki < 8; ++kki) {
                const int kk = (wv << 4) + (kki << 1) + kx, kg = k0 + kk;
                const float4* rk = (const float4*)&Klds[kk][hp * 32];
                float s0 = 0.f, s1 = 0.f;
                #pragma unroll
                for (int i = 0; i < 4; ++i) {
                    float4 ka = rk[i], kb2 = rk[4 + i];
                    s0 = fmaf(ka.x, qv[0][i].x, s0); s0 = fmaf(ka.y, qv[0][i].y, s0);
                    s0 = fmaf(ka.z, qv[0][i].z, s0); s0 = fmaf(ka.w, qv[0][i].w, s0);
                    s1 = fmaf(kb2.x, qv[1][i].x, s1); s1 = fmaf(kb2.y, qv[1][i].y, s1);
                    s1 = fmaf(kb2.z, qv[1][i].z, s1); s1 = fmaf(kb2.w, qv[1][i].w, s1);
                }
                const bool valid = qvalid && (kg <= qrow);
                const float p0 = (valid ? __expf(s0 * 0.125f) : 0.f) * iz0;
                const float p1 = (valid ? __expf(s1 * 0.125f) : 0.f) * iz1;
                float asum = p0 + p1;
                const float aoth = __shfl_xor(asum, 32, 64);
                if (hp == 0) alds[ql][kk] = 0.25f * (asum + aoth);
                const float4* rv = (const float4*)&Vlds[kk][hp * 32];
                #pragma unroll
                for (int i = 0; i < 4; ++i) {
                    float4 va = rv[i], vb = rv[4 + i];
                    o4[0][i].x = fmaf(p0, va.x, o4[0][i].x);
                    o4[0][i].y = fmaf(p0, va.y, o4[0][i].y);
                    o4[0][i].z = fmaf(p0, va.z, o4[0][i].z);
                    o4[0][i].w = fmaf(p0, va.w, o4[0][i].w);
                    o4[1][i].x = fmaf(p1, vb.x, o4[1][i].x);
                    o4[1][i].y = fmaf(p1, vb.y, o4[1][i].y);
                    o4[1][i].z = fmaf(p1, vb.z, o4[1][i].z);
                    o4[1][i].w = fmaf(p1, vb.w, o4[1][i].w);
                }
            }
            __syncthreads();
        }

        // O reduce over kx, then cross-wave via obuf (aliases Klds pool)
        #pragma unroll
        for (int e = 0; e < 2; ++e)
            #pragma unroll
            for (int i = 0; i < 4; ++i) {
                o4[e][i].x += __shfl_xor(o4[e][i].x, 16, 64);
                o4[e][i].y += __shfl_xor(o4[e][i].y, 16, 64);
                o4[e][i].z += __shfl_xor(o4[e][i].z, 16, 64);
                o4[e][i].w += __shfl_xor(o4[e][i].w, 16, 64);
            }
        float (*obuf)[16][68] = (float(*)[16][68])pool;   // 2*16*68 floats < Klds

        // flush last amean tile (alds) in parallel with obuf phase 1
        if (ntiles > 0) {
            const int kp = (ntiles - 1) << 6;
            int r = t >> 4, c4 = t & 15;
            float4 w4 = make_float4(alds[r][c4 * 4], alds[r][c4 * 4 + 1],
                                    alds[r][c4 * 4 + 2], alds[r][c4 * 4 + 3]);
            *(float4*)&amean[((size_t)(b * NS + q0 + r)) * NS + kp + c4 * 4] = w4;
        }
        if (wv < 2 && kx == 0) {
            #pragma unroll
            for (int e = 0; e < 2; ++e)
                #pragma unroll
                for (int i = 0; i < 4; ++i) {
                    int j = hp * 32 + e * 16 + i * 4;
                    obuf[wv][ql][j + 0] = o4[e][i].x;
                    obuf[wv][ql][j + 1] = o4[e][i].y;
                    obuf[wv][ql][j + 2] = o4[e][i].z;
                    obuf[wv][ql][j + 3] = o4[e][i].w;
                }
        }
        __syncthreads();
        if (wv >= 2 && kx == 0) {
            #pragma unroll
            for (int e = 0; e < 2; ++e)
                #pragma unroll
                for (int i = 0; i < 4; ++i) {
                    int j = hp * 32 + e * 16 + i * 4;
                    obuf[wv - 2][ql][j + 0] += o4[e][i].x;
                    obuf[wv - 2][ql][j + 1] += o4[e][i].y;
                    obuf[wv - 2][ql][j + 2] += o4[e][i].z;
                    obuf[wv - 2][ql][j + 3] += o4[e][i].w;
                }
        }
        __syncthreads();
        {
            int r = t >> 4, c4 = t & 15;
            float4 w4;
            w4.x = obuf[0][r][c4 * 4 + 0] + obuf[1][r][c4 * 4 + 0];
            w4.y = obuf[0][r][c4 * 4 + 1] + obuf[1][r][c4 * 4 + 1];
            w4.z = obuf[0][r][c4 * 4 + 2] + obuf[1][r][c4 * 4 + 2];
            w4.w = obuf[0][r][c4 * 4 + 3] + obuf[1][r][c4 * 4 + 3];
            *(float4*)&out[((size_t)(b * NS + q0 + r)) * NHID + c4 * 4] = w4;
        }

        // zero-fill amean columns beyond processed tiles
        const int kz = ntiles << 6;
        const int nz4 = (NS - kz) >> 2;
        const float4 z4 = make_float4(0.f, 0.f, 0.f, 0.f);
        for (int r = 0; r < 16; ++r) {
            for (int c4 = t; c4 < nz4; c4 += 256) {
                *(float4*)&amean[((size_t)(b * NS + q0 + r)) * NS + kz + c4 * 4] = z4;
            }
        }
        __syncthreads();   // obuf (pool) must be fully read before next half restages
    }
}

// ---------------------------------------------------------------------------
// Kernel 3: residual + LN1 + FFN(GELU exact) + residual + LN2 (unchanged).
// ---------------------------------------------------------------------------
__device__ __forceinline__ float wsum(float v) {
    #pragma unroll
    for (int o = 32; o > 0; o >>= 1) v += __shfl_xor(v, o, 64);
    return v;
}

__global__ __launch_bounds__(256) void ffn_kernel(
    const float* __restrict__ x, const float* __restrict__ aout,
    const float* __restrict__ W1, const float* __restrict__ b1,
    const float* __restrict__ W2, const float* __restrict__ b2,
    const float* __restrict__ g1, const float* __restrict__ be1,
    const float* __restrict__ g2, const float* __restrict__ be2,
    float* __restrict__ y)
{
    __shared__ float w1t[64][65], w2t[64][65];
    __shared__ float n1sh[4][64], h1sh[4][64];
    int t = threadIdx.x;
    for (int i = t; i < 4096; i += 256) {
        int c = i >> 6, j = i & 63;
        w1t[j][c] = W1[i];
        w2t[j][c] = W2[i];
    }
    __syncthreads();
    int wv = t >> 6, d = t & 63;
    size_t row = (size_t)blockIdx.x * 4 + wv;

    float o1 = x[row * 64 + d] + aout[row * 64 + d];
    float mu = wsum(o1) * (1.f / 64.f);
    float diff = o1 - mu;
    float var = wsum(diff * diff) * (1.f / 64.f);
    float n1 = diff * rsqrtf(var + LN_EPS) * g1[d] + be1[d];
    n1sh[wv][d] = n1;
    __syncthreads();
    float acc = b1[d];
    #pragma unroll
    for (int j = 0; j < 64; ++j) acc = fmaf(n1sh[wv][j], w1t[j][d], acc);
    float ge = 0.5f * acc * (1.f + erff(acc * 0.70710678118654752f));
    h1sh[wv][d] = ge;
    __syncthreads();
    float acc2 = b2[d];
    #pragma unroll
    for (int j = 0; j < 64; ++j) acc2 = fmaf(h1sh[wv][j], w2t[j][d], acc2);
    float z = n1 + acc2;
    float mu2 = wsum(z) * (1.f / 64.f);
    float d2 = z - mu2;
    float var2 = wsum(d2 * d2) * (1.f / 64.f);
    float yv = d2 * rsqrtf(var2 + LN_EPS) * g2[d] + be2[d];
    y[row * 64 + d] = yv;
}

// ---------------------------------------------------------------------------
extern "C" void kernel_launch(void* const* d_in, const int* in_sizes, int n_in,
                              void* d_out, int out_size, void* d_ws, size_t ws_size,
                              hipStream_t stream) {
    const float* x   = (const float*)d_in[0];
    const int* lengths = (const int*)d_in[1];
    const float* Wq  = (const float*)d_in[3];
    const float* bq  = (const float*)d_in[4];
    const float* Wk  = (const float*)d_in[5];
    const float* bk  = (const float*)d_in[6];
    const float* Wv  = (const float*)d_in[7];
    const float* bv  = (const float*)d_in[8];
    const float* W1  = (const float*)d_in[9];
    const float* b1  = (const float*)d_in[10];
    const float* W2  = (const float*)d_in[11];
    const float* b2  = (const float*)d_in[12];
    const float* g1  = (const float*)d_in[13];
    const float* be1 = (const float*)d_in[14];
    const float* g2  = (const float*)d_in[15];
    const float* be2 = (const float*)d_in[16];

    float* y     = (float*)d_out;                       // [B,S,64]
    float* amean = y + (size_t)NB * NS * NHID;          // [B,S,S]

    float* qw    = (float*)d_ws;                        // [B,NH,S,DH]
    float* kw    = qw + (size_t)NB * NHEADS * NS * NDH;
    float* vw    = kw + (size_t)NB * NHEADS * NS * NDH;
    float* aoutw = vw + (size_t)NB * NHEADS * NS * NDH; // [B,S,64]

    hipLaunchKernelGGL(qkv_kernel, dim3(NB * NS / 32), dim3(256), 0, stream,
                       x, Wq, bq, Wk, bk, Wv, bv, qw, kw, vw);
    hipLaunchKernelGGL(attn4_kernel, dim3(512), dim3(256), 0, stream,
                       qw, kw, vw, lengths, amean, aoutw);
    hipLaunchKernelGGL(ffn_kernel, dim3(NB * NS / 4), dim3(256), 0, stream,
                       x, aoutw, W1, b1, W2, b2, g1, be1, g2, be2, y);
}

// Round 6
// 622.751 us; speedup vs baseline: 1.0515x; 1.0515x over previous
//
#include <hip/hip_runtime.h>

#define NB 16
#define NS 1024
#define NHID 64
#define NHEADS 4
#define NDH 16
#define LN_EPS 1e-5f

// ---------------------------------------------------------------------------
// Kernel 1: QKV projection (unchanged).
// ---------------------------------------------------------------------------
__global__ __launch_bounds__(256) void qkv_kernel(
    const float* __restrict__ x,
    const float* __restrict__ Wq, const float* __restrict__ bq,
    const float* __restrict__ Wk, const float* __restrict__ bk,
    const float* __restrict__ Wv, const float* __restrict__ bv,
    float* __restrict__ qo, float* __restrict__ ko, float* __restrict__ vo)
{
    __shared__ float wqt[64][65], wkt[64][65], wvt[64][65];
    __shared__ float xs[32][64];
    int t = threadIdx.x;
    int row0 = blockIdx.x * 32;
    for (int i = t; i < 4096; i += 256) {
        int c = i >> 6, j = i & 63;
        wqt[j][c] = Wq[i];
        wkt[j][c] = Wk[i];
        wvt[j][c] = Wv[i];
    }
    for (int i = t; i < 2048; i += 256) {
        xs[i >> 6][i & 63] = x[(size_t)row0 * 64 + i];
    }
    __syncthreads();
    int c = t & 63, rq = t >> 6;
    int h = c >> 4, d = c & 15;
    float bqv = bq[c], bkv = bk[c], bvv = bv[c];
    for (int rr = 0; rr < 8; ++rr) {
        int r = rq * 8 + rr;
        float aq = bqv, ak = bkv, av = bvv;
        #pragma unroll
        for (int j = 0; j < 64; ++j) {
            float xv = xs[r][j];
            aq = fmaf(xv, wqt[j][c], aq);
            ak = fmaf(xv, wkt[j][c], ak);
            av = fmaf(xv, wvt[j][c], av);
        }
        int srow = row0 + r;
        int b_ = srow >> 10, s_ = srow & 1023;
        size_t o = (((size_t)(b_ * NHEADS + h)) * NS + s_) * NDH + d;
        qo[o] = aq; ko[o] = ak; vo[o] = av;
    }
}

// ---------------------------------------------------------------------------
// Kernel 2 (attn5): identical body to round-5 attn4, but grid mapping restored
// to round-3 style: blockIdx.y = batch, blockIdx.x = pair index. Same-batch
// blocks are contiguous in linear block id -> stay on one XCD -> K/V (512 KB)
// stays L2-resident (round-3 evidence: 24 MB FETCH vs round-5's 330 MB).
// Causal pairing (q-tiles p and 63-p) keeps per-block work uniform.
// ---------------------------------------------------------------------------
__global__ __launch_bounds__(256, 3) void attn5_kernel(
    const float* __restrict__ q, const float* __restrict__ k,
    const float* __restrict__ v, const int* __restrict__ lengths,
    float* __restrict__ amean,   // [B,S,S]
    float* __restrict__ out)     // [B,S,64]
{
    __shared__ float pool[2 * 64 * 68];      // Klds | Vlds ; obuf aliases Klds
    float (*Klds)[68] = (float(*)[68])pool;
    float (*Vlds)[68] = (float(*)[68])(pool + 64 * 68);
    __shared__ float alds[16][65];
    __shared__ float zlds[4][32][2];

    const int t  = threadIdx.x;
    const int wv = t >> 6, ln = t & 63;
    const int hp = ln >> 5;
    const int kx = (ln >> 4) & 1;
    const int ql = ln & 15;
    const int pr = blockIdx.x;               // 0..31  (pair index)
    const int b  = blockIdx.y;               // batch: contiguous ids share b
    const int len = lengths[b];

    for (int half = 0; half < 2; ++half) {
        const int qt = half ? (63 - pr) : pr;
        const int q0 = qt << 4;
        const int qrow = q0 + ql;
        const bool qvalid = qrow < len;

        // Q rows -> registers (heads 2hp, 2hp+1)
        float4 qv[2][4];
        #pragma unroll
        for (int e = 0; e < 2; ++e) {
            const float4* qp = (const float4*)
                &q[(((size_t)(b * NHEADS + hp * 2 + e)) * NS + qrow) * NDH];
            qv[e][0] = qp[0]; qv[e][1] = qp[1]; qv[e][2] = qp[2]; qv[e][3] = qp[3];
        }

        const int nk = (len <= q0) ? 0 : min(q0 + 16, len);
        const int ntiles = (nk + 63) >> 6;

        // ---------------- pass 1: Z ----------------
        float Z0 = 0.f, Z1 = 0.f;
        for (int tile = 0; tile < ntiles; ++tile) {
            const int k0 = tile << 6;
            #pragma unroll
            for (int i = 0; i < 4; ++i) {
                int idx = t + 256 * i, kk = idx & 63, j4 = idx >> 6;
                *(float4*)&Klds[kk][j4 * 4] = *(const float4*)
                    &k[(((size_t)(b * NHEADS + (j4 >> 2))) * NS + k0 + kk) * NDH + (j4 & 3) * 4];
            }
            __syncthreads();
            #pragma unroll
            for (int kki = 0; kki < 8; ++kki) {
                const int kk = (wv << 4) + (kki << 1) + kx, kg = k0 + kk;
                const float4* rk = (const float4*)&Klds[kk][hp * 32];
                float s0 = 0.f, s1 = 0.f;
                #pragma unroll
                for (int i = 0; i < 4; ++i) {
                    float4 ka = rk[i], kb2 = rk[4 + i];
                    s0 = fmaf(ka.x, qv[0][i].x, s0); s0 = fmaf(ka.y, qv[0][i].y, s0);
                    s0 = fmaf(ka.z, qv[0][i].z, s0); s0 = fmaf(ka.w, qv[0][i].w, s0);
                    s1 = fmaf(kb2.x, qv[1][i].x, s1); s1 = fmaf(kb2.y, qv[1][i].y, s1);
                    s1 = fmaf(kb2.z, qv[1][i].z, s1); s1 = fmaf(kb2.w, qv[1][i].w, s1);
                }
                const bool valid = qvalid && (kg <= qrow);
                Z0 += valid ? __expf(s0 * 0.125f) : 0.f;
                Z1 += valid ? __expf(s1 * 0.125f) : 0.f;
            }
            __syncthreads();
        }
        Z0 += __shfl_xor(Z0, 16, 64);
        Z1 += __shfl_xor(Z1, 16, 64);
        if (kx == 0) {
            zlds[wv][hp * 16 + ql][0] = Z0;
            zlds[wv][hp * 16 + ql][1] = Z1;
        }
        __syncthreads();
        const int zi = hp * 16 + ql;
        const float zt0 = zlds[0][zi][0] + zlds[1][zi][0] + zlds[2][zi][0] + zlds[3][zi][0];
        const float zt1 = zlds[0][zi][1] + zlds[1][zi][1] + zlds[2][zi][1] + zlds[3][zi][1];
        const float iz0 = (zt0 > 0.f) ? 1.f / zt0 : 0.f;
        const float iz1 = (zt1 > 0.f) ? 1.f / zt1 : 0.f;
        __syncthreads();

        // ---------------- pass 2: probs, amean, PV ----------------
        float4 o4[2][4];
        #pragma unroll
        for (int e = 0; e < 2; ++e)
            #pragma unroll
            for (int i = 0; i < 4; ++i) o4[e][i] = make_float4(0.f, 0.f, 0.f, 0.f);

        for (int tile = 0; tile < ntiles; ++tile) {
            const int k0 = tile << 6;
            if (tile > 0) {                       // flush previous amean tile
                const int kp = k0 - 64;
                int r = t >> 4, c4 = t & 15;
                float4 w4 = make_float4(alds[r][c4 * 4], alds[r][c4 * 4 + 1],
                                        alds[r][c4 * 4 + 2], alds[r][c4 * 4 + 3]);
                *(float4*)&amean[((size_t)(b * NS + q0 + r)) * NS + kp + c4 * 4] = w4;
            }
            #pragma unroll
            for (int i = 0; i < 4; ++i) {
                int idx = t + 256 * i, kk = idx & 63, j4 = idx >> 6;
                size_t goff = (((size_t)(b * NHEADS + (j4 >> 2))) * NS + k0 + kk) * NDH + (j4 & 3) * 4;
                *(float4*)&Klds[kk][j4 * 4] = *(const float4*)&k[goff];
                *(float4*)&Vlds[kk][j4 * 4] = *(const float4*)&v[goff];
            }
            __syncthreads();
            #pragma unroll
            for (int kki = 0; kki < 8; ++kki) {
                const int kk = (wv << 4) + (kki << 1) + kx, kg = k0 + kk;
                const float4* rk = (const float4*)&Klds[kk][hp * 32];
                float s0 = 0.f, s1 = 0.f;
                #pragma unroll
                for (int i = 0; i < 4; ++i) {
                    float4 ka = rk[i], kb2 = rk[4 + i];
                    s0 = fmaf(ka.x, qv[0][i].x, s0); s0 = fmaf(ka.y, qv[0][i].y, s0);
                    s0 = fmaf(ka.z, qv[0][i].z, s0); s0 = fmaf(ka.w, qv[0][i].w, s0);
                    s1 = fmaf(kb2.x, qv[1][i].x, s1); s1 = fmaf(kb2.y, qv[1][i].y, s1);
                    s1 = fmaf(kb2.z, qv[1][i].z, s1); s1 = fmaf(kb2.w, qv[1][i].w, s1);
                }
                const bool valid = qvalid && (kg <= qrow);
                const float p0 = (valid ? __expf(s0 * 0.125f) : 0.f) * iz0;
                const float p1 = (valid ? __expf(s1 * 0.125f) : 0.f) * iz1;
                float asum = p0 + p1;
                const float aoth = __shfl_xor(asum, 32, 64);
                if (hp == 0) alds[ql][kk] = 0.25f * (asum + aoth);
                const float4* rv = (const float4*)&Vlds[kk][hp * 32];
                #pragma unroll
                for (int i = 0; i < 4; ++i) {
                    float4 va = rv[i], vb = rv[4 + i];
                    o4[0][i].x = fmaf(p0, va.x, o4[0][i].x);
                    o4[0][i].y = fmaf(p0, va.y, o4[0][i].y);
                    o4[0][i].z = fmaf(p0, va.z, o4[0][i].z);
                    o4[0][i].w = fmaf(p0, va.w, o4[0][i].w);
                    o4[1][i].x = fmaf(p1, vb.x, o4[1][i].x);
                    o4[1][i].y = fmaf(p1, vb.y, o4[1][i].y);
                    o4[1][i].z = fmaf(p1, vb.z, o4[1][i].z);
                    o4[1][i].w = fmaf(p1, vb.w, o4[1][i].w);
                }
            }
            __syncthreads();
        }

        // O reduce over kx, then cross-wave via obuf (aliases Klds pool)
        #pragma unroll
        for (int e = 0; e < 2; ++e)
            #pragma unroll
            for (int i = 0; i < 4; ++i) {
                o4[e][i].x += __shfl_xor(o4[e][i].x, 16, 64);
                o4[e][i].y += __shfl_xor(o4[e][i].y, 16, 64);
                o4[e][i].z += __shfl_xor(o4[e][i].z, 16, 64);
                o4[e][i].w += __shfl_xor(o4[e][i].w, 16, 64);
            }
        float (*obuf)[16][68] = (float(*)[16][68])pool;   // 2*16*68 floats < Klds

        // flush last amean tile (alds) in parallel with obuf phase 1
        if (ntiles > 0) {
            const int kp = (ntiles - 1) << 6;
            int r = t >> 4, c4 = t & 15;
            float4 w4 = make_float4(alds[r][c4 * 4], alds[r][c4 * 4 + 1],
                                    alds[r][c4 * 4 + 2], alds[r][c4 * 4 + 3]);
            *(float4*)&amean[((size_t)(b * NS + q0 + r)) * NS + kp + c4 * 4] = w4;
        }
        if (wv < 2 && kx == 0) {
            #pragma unroll
            for (int e = 0; e < 2; ++e)
                #pragma unroll
                for (int i = 0; i < 4; ++i) {
                    int j = hp * 32 + e * 16 + i * 4;
                    obuf[wv][ql][j + 0] = o4[e][i].x;
                    obuf[wv][ql][j + 1] = o4[e][i].y;
                    obuf[wv][ql][j + 2] = o4[e][i].z;
                    obuf[wv][ql][j + 3] = o4[e][i].w;
                }
        }
        __syncthreads();
        if (wv >= 2 && kx == 0) {
            #pragma unroll
            for (int e = 0; e < 2; ++e)
                #pragma unroll
                for (int i = 0; i < 4; ++i) {
                    int j = hp * 32 + e * 16 + i * 4;
                    obuf[wv - 2][ql][j + 0] += o4[e][i].x;
                    obuf[wv - 2][ql][j + 1] += o4[e][i].y;
                    obuf[wv - 2][ql][j + 2] += o4[e][i].z;
                    obuf[wv - 2][ql][j + 3] += o4[e][i].w;
                }
        }
        __syncthreads();
        {
            int r = t >> 4, c4 = t & 15;
            float4 w4;
            w4.x = obuf[0][r][c4 * 4 + 0] + obuf[1][r][c4 * 4 + 0];
            w4.y = obuf[0][r][c4 * 4 + 1] + obuf[1][r][c4 * 4 + 1];
            w4.z = obuf[0][r][c4 * 4 + 2] + obuf[1][r][c4 * 4 + 2];
            w4.w = obuf[0][r][c4 * 4 + 3] + obuf[1][r][c4 * 4 + 3];
            *(float4*)&out[((size_t)(b * NS + q0 + r)) * NHID + c4 * 4] = w4;
        }

        // zero-fill amean columns beyond processed tiles
        const int kz = ntiles << 6;
        const int nz4 = (NS - kz) >> 2;
        const float4 z4 = make_float4(0.f, 0.f, 0.f, 0.f);
        for (int r = 0; r < 16; ++r) {
            for (int c4 = t; c4 < nz4; c4 += 256) {
                *(float4*)&amean[((size_t)(b * NS + q0 + r)) * NS + kz + c4 * 4] = z4;
            }
        }
        __syncthreads();   // obuf (pool) must be fully read before next half restages
    }
}

// ---------------------------------------------------------------------------
// Kernel 3: residual + LN1 + FFN(GELU exact) + residual + LN2 (unchanged).
// ---------------------------------------------------------------------------
__device__ __forceinline__ float wsum(float v) {
    #pragma unroll
    for (int o = 32; o > 0; o >>= 1) v += __shfl_xor(v, o, 64);
    return v;
}

__global__ __launch_bounds__(256) void ffn_kernel(
    const float* __restrict__ x, const float* __restrict__ aout,
    const float* __restrict__ W1, const float* __restrict__ b1,
    const float* __restrict__ W2, const float* __restrict__ b2,
    const float* __restrict__ g1, const float* __restrict__ be1,
    const float* __restrict__ g2, const float* __restrict__ be2,
    float* __restrict__ y)
{
    __shared__ float w1t[64][65], w2t[64][65];
    __shared__ float n1sh[4][64], h1sh[4][64];
    int t = threadIdx.x;
    for (int i = t; i < 4096; i += 256) {
        int c = i >> 6, j = i & 63;
        w1t[j][c] = W1[i];
        w2t[j][c] = W2[i];
    }
    __syncthreads();
    int wv = t >> 6, d = t & 63;
    size_t row = (size_t)blockIdx.x * 4 + wv;

    float o1 = x[row * 64 + d] + aout[row * 64 + d];
    float mu = wsum(o1) * (1.f / 64.f);
    float diff = o1 - mu;
    float var = wsum(diff * diff) * (1.f / 64.f);
    float n1 = diff * rsqrtf(var + LN_EPS) * g1[d] + be1[d];
    n1sh[wv][d] = n1;
    __syncthreads();
    float acc = b1[d];
    #pragma unroll
    for (int j = 0; j < 64; ++j) acc = fmaf(n1sh[wv][j], w1t[j][d], acc);
    float ge = 0.5f * acc * (1.f + erff(acc * 0.70710678118654752f));
    h1sh[wv][d] = ge;
    __syncthreads();
    float acc2 = b2[d];
    #pragma unroll
    for (int j = 0; j < 64; ++j) acc2 = fmaf(h1sh[wv][j], w2t[j][d], acc2);
    float z = n1 + acc2;
    float mu2 = wsum(z) * (1.f / 64.f);
    float d2 = z - mu2;
    float var2 = wsum(d2 * d2) * (1.f / 64.f);
    float yv = d2 * rsqrtf(var2 + LN_EPS) * g2[d] + be2[d];
    y[row * 64 + d] = yv;
}

// ---------------------------------------------------------------------------
extern "C" void kernel_launch(void* const* d_in, const int* in_sizes, int n_in,
                              void* d_out, int out_size, void* d_ws, size_t ws_size,
                              hipStream_t stream) {
    const float* x   = (const float*)d_in[0];
    const int* lengths = (const int*)d_in[1];
    const float* Wq  = (const float*)d_in[3];
    const float* bq  = (const float*)d_in[4];
    const float* Wk  = (const float*)d_in[5];
    const float* bk  = (const float*)d_in[6];
    const float* Wv  = (const float*)d_in[7];
    const float* bv  = (const float*)d_in[8];
    const float* W1  = (const float*)d_in[9];
    const float* b1  = (const float*)d_in[10];
    const float* W2  = (const float*)d_in[11];
    const float* b2  = (const float*)d_in[12];
    const float* g1  = (const float*)d_in[13];
    const float* be1 = (const float*)d_in[14];
    const float* g2  = (const float*)d_in[15];
    const float* be2 = (const float*)d_in[16];

    float* y     = (float*)d_out;                       // [B,S,64]
    float* amean = y + (size_t)NB * NS * NHID;          // [B,S,S]

    float* qw    = (float*)d_ws;                        // [B,NH,S,DH]
    float* kw    = qw + (size_t)NB * NHEADS * NS * NDH;
    float* vw    = kw + (size_t)NB * NHEADS * NS * NDH;
    float* aoutw = vw + (size_t)NB * NHEADS * NS * NDH; // [B,S,64]

    hipLaunchKernelGGL(qkv_kernel, dim3(NB * NS / 32), dim3(256), 0, stream,
                       x, Wq, bq, Wk, bk, Wv, bv, qw, kw, vw);
    hipLaunchKernelGGL(attn5_kernel, dim3(32, NB), dim3(256), 0, stream,
                       qw, kw, vw, lengths, amean, aoutw);
    hipLaunchKernelGGL(ffn_kernel, dim3(NB * NS / 4), dim3(256), 0, stream,
                       x, aoutw, W1, b1, W2, b2, g1, be1, g2, be2, y);
}

// Round 7
// 322.077 us; speedup vs baseline: 2.0331x; 1.9335x over previous
//
#include <hip/hip_runtime.h>

#define NB 16
#define NS 1024
#define NHID 64
#define NHEADS 4
#define NDH 16
#define LN_EPS 1e-5f

// ---------------------------------------------------------------------------
// Kernel 1: QKV projection (unchanged).
// ---------------------------------------------------------------------------
__global__ __launch_bounds__(256) void qkv_kernel(
    const float* __restrict__ x,
    const float* __restrict__ Wq, const float* __restrict__ bq,
    const float* __restrict__ Wk, const float* __restrict__ bk,
    const float* __restrict__ Wv, const float* __restrict__ bv,
    float* __restrict__ qo, float* __restrict__ ko, float* __restrict__ vo)
{
    __shared__ float wqt[64][65], wkt[64][65], wvt[64][65];
    __shared__ float xs[32][64];
    int t = threadIdx.x;
    int row0 = blockIdx.x * 32;
    for (int i = t; i < 4096; i += 256) {
        int c = i >> 6, j = i & 63;
        wqt[j][c] = Wq[i];
        wkt[j][c] = Wk[i];
        wvt[j][c] = Wv[i];
    }
    for (int i = t; i < 2048; i += 256) {
        xs[i >> 6][i & 63] = x[(size_t)row0 * 64 + i];
    }
    __syncthreads();
    int c = t & 63, rq = t >> 6;
    int h = c >> 4, d = c & 15;
    float bqv = bq[c], bkv = bk[c], bvv = bv[c];
    for (int rr = 0; rr < 8; ++rr) {
        int r = rq * 8 + rr;
        float aq = bqv, ak = bkv, av = bvv;
        #pragma unroll
        for (int j = 0; j < 64; ++j) {
            float xv = xs[r][j];
            aq = fmaf(xv, wqt[j][c], aq);
            ak = fmaf(xv, wkt[j][c], ak);
            av = fmaf(xv, wvt[j][c], av);
        }
        int srow = row0 + r;
        int b_ = srow >> 10, s_ = srow & 1023;
        size_t o = (((size_t)(b_ * NHEADS + h)) * NS + s_) * NDH + d;
        qo[o] = aq; ko[o] = ak; vo[o] = av;
    }
}

// ---------------------------------------------------------------------------
// Kernel 2 (attn6): FUSED causal pairing, lockstep k-sweep.
// Block = (b, pr): q-tiles A=pr and B=63-pr (16 rows each), ONE k-tile sweep,
// both tiles computed per staged k-tile (A guarded by tile<ntA). Keeps all
// blocks of a batch phase-coherent over k-tiles -> L2-resident staging
// (round 3 evidence) while work/block is uniform (~17 tile-units).
// Wave = head h. Lane: kx = ln>>4 (k-quarter), ql = ln&15 (q-row).
// K/V LDS reads are wave-uniform (broadcast). Z/O reduced by shfl over kx.
// amean head-sum via LDS atomicAdd (ds_add_f32), per-head k-rotation to
// avoid same-address contention. VGPR target <=128 for (256,2).
// ---------------------------------------------------------------------------
__device__ __forceinline__ float dot16q(const float4 a, const float4 b2,
                                        const float4 c, const float4 d,
                                        const float4* qv) {
    return a.x*qv[0].x + a.y*qv[0].y + a.z*qv[0].z + a.w*qv[0].w
         + b2.x*qv[1].x + b2.y*qv[1].y + b2.z*qv[1].z + b2.w*qv[1].w
         + c.x*qv[2].x + c.y*qv[2].y + c.z*qv[2].z + c.w*qv[2].w
         + d.x*qv[3].x + d.y*qv[3].y + d.z*qv[3].z + d.w*qv[3].w;
}

__global__ __launch_bounds__(256, 2) void attn6_kernel(
    const float* __restrict__ q, const float* __restrict__ k,
    const float* __restrict__ v, const int* __restrict__ lengths,
    float* __restrict__ amean,   // [B,S,S]
    float* __restrict__ out)     // [B,S,64]
{
    __shared__ float Klds[64][68];
    __shared__ float Vlds[64][68];
    __shared__ float alds[2][16][65];   // head-summed 0.25*p for tiles A,B

    const int t  = threadIdx.x;
    const int h  = t >> 6;              // wave = head
    const int ln = t & 63;
    const int ql = ln & 15;             // q-row within tile
    const int kx = ln >> 4;             // k-quarter (16 k's each)
    const int pr = blockIdx.x;          // 0..31
    const int b  = blockIdx.y;
    const int len = lengths[b];

    const int q0A = pr << 4, q0B = (63 - pr) << 4;
    const int qrowA = q0A + ql, qrowB = q0B + ql;
    const bool qvA = qrowA < len, qvB = qrowB < len;

    // Q rows -> registers (head h)
    float4 qA[4], qB[4];
    {
        const float4* p = (const float4*)&q[(((size_t)(b * NHEADS + h)) * NS + qrowA) * NDH];
        qA[0] = p[0]; qA[1] = p[1]; qA[2] = p[2]; qA[3] = p[3];
        const float4* p2 = (const float4*)&q[(((size_t)(b * NHEADS + h)) * NS + qrowB) * NDH];
        qB[0] = p2[0]; qB[1] = p2[1]; qB[2] = p2[2]; qB[3] = p2[3];
    }

    const int nkA = (len <= q0A) ? 0 : min(q0A + 16, len);
    const int ntA = (nkA + 63) >> 6;
    const int nkB = (len <= q0B) ? 0 : min(q0B + 16, len);
    const int ntB = (nkB + 63) >> 6;
    const int ntM = max(ntA, ntB);

    // ---------------- pass 1: ZA, ZB ----------------
    float ZA = 0.f, ZB = 0.f;
    for (int tile = 0; tile < ntM; ++tile) {
        const int k0 = tile << 6;
        #pragma unroll
        for (int i = 0; i < 4; ++i) {
            int idx = t + 256 * i, kk = idx & 63, j4 = idx >> 6;
            *(float4*)&Klds[kk][j4 * 4] = *(const float4*)
                &k[(((size_t)(b * NHEADS + (j4 >> 2))) * NS + k0 + kk) * NDH + (j4 & 3) * 4];
        }
        __syncthreads();
        const bool doA = tile < ntA, doB = tile < ntB;
        #pragma unroll 4
        for (int kki = 0; kki < 16; ++kki) {
            const int kk = (kx << 4) + kki, kg = k0 + kk;
            const float4* rk = (const float4*)&Klds[kk][h * 16];
            const float4 k0v = rk[0], k1v = rk[1], k2v = rk[2], k3v = rk[3];
            if (doA) {
                float s = dot16q(k0v, k1v, k2v, k3v, qA);
                ZA += (qvA && kg <= qrowA) ? __expf(s * 0.125f) : 0.f;
            }
            if (doB) {
                float s = dot16q(k0v, k1v, k2v, k3v, qB);
                ZB += (qvB && kg <= qrowB) ? __expf(s * 0.125f) : 0.f;
            }
        }
        __syncthreads();
    }
    ZA += __shfl_xor(ZA, 16, 64); ZA += __shfl_xor(ZA, 32, 64);
    ZB += __shfl_xor(ZB, 16, 64); ZB += __shfl_xor(ZB, 32, 64);
    const float izA = (ZA > 0.f) ? 1.f / ZA : 0.f;
    const float izB = (ZB > 0.f) ? 1.f / ZB : 0.f;

    // zero alds before accumulation
    for (int i = t; i < 2 * 16 * 65; i += 256) ((float*)alds)[i] = 0.f;

    // ---------------- pass 2: probs, amean, PV ----------------
    float4 oA[4], oB[4];
    #pragma unroll
    for (int i = 0; i < 4; ++i) {
        oA[i] = make_float4(0.f, 0.f, 0.f, 0.f);
        oB[i] = make_float4(0.f, 0.f, 0.f, 0.f);
    }

    for (int tile = 0; tile < ntM; ++tile) {
        const int k0 = tile << 6;
        #pragma unroll
        for (int i = 0; i < 4; ++i) {
            int idx = t + 256 * i, kk = idx & 63, j4 = idx >> 6;
            size_t goff = (((size_t)(b * NHEADS + (j4 >> 2))) * NS + k0 + kk) * NDH + (j4 & 3) * 4;
            *(float4*)&Klds[kk][j4 * 4] = *(const float4*)&k[goff];
            *(float4*)&Vlds[kk][j4 * 4] = *(const float4*)&v[goff];
        }
        __syncthreads();   // staging + alds zeros/flush-zeros visible
        const bool doA = tile < ntA, doB = tile < ntB;
        #pragma unroll 4
        for (int kki = 0; kki < 16; ++kki) {
            // per-head rotation: heads touch different kk at any moment
            const int kk = (kx << 4) + ((kki + h * 4) & 15);
            const int kg = k0 + kk;
            const float4* rk = (const float4*)&Klds[kk][h * 16];
            const float4 k0v = rk[0], k1v = rk[1], k2v = rk[2], k3v = rk[3];
            const float4* rv = (const float4*)&Vlds[kk][h * 16];
            const float4 v0v = rv[0], v1v = rv[1], v2v = rv[2], v3v = rv[3];
            if (doA) {
                float s = dot16q(k0v, k1v, k2v, k3v, qA);
                const bool valid = qvA && (kg <= qrowA);
                const float p = (valid ? __expf(s * 0.125f) : 0.f) * izA;
                atomicAdd(&alds[0][ql][kk], 0.25f * p);
                oA[0].x = fmaf(p, v0v.x, oA[0].x); oA[0].y = fmaf(p, v0v.y, oA[0].y);
                oA[0].z = fmaf(p, v0v.z, oA[0].z); oA[0].w = fmaf(p, v0v.w, oA[0].w);
                oA[1].x = fmaf(p, v1v.x, oA[1].x); oA[1].y = fmaf(p, v1v.y, oA[1].y);
                oA[1].z = fmaf(p, v1v.z, oA[1].z); oA[1].w = fmaf(p, v1v.w, oA[1].w);
                oA[2].x = fmaf(p, v2v.x, oA[2].x); oA[2].y = fmaf(p, v2v.y, oA[2].y);
                oA[2].z = fmaf(p, v2v.z, oA[2].z); oA[2].w = fmaf(p, v2v.w, oA[2].w);
                oA[3].x = fmaf(p, v3v.x, oA[3].x); oA[3].y = fmaf(p, v3v.y, oA[3].y);
                oA[3].z = fmaf(p, v3v.z, oA[3].z); oA[3].w = fmaf(p, v3v.w, oA[3].w);
            }
            if (doB) {
                float s = dot16q(k0v, k1v, k2v, k3v, qB);
                const bool valid = qvB && (kg <= qrowB);
                const float p = (valid ? __expf(s * 0.125f) : 0.f) * izB;
                atomicAdd(&alds[1][ql][kk], 0.25f * p);
                oB[0].x = fmaf(p, v0v.x, oB[0].x); oB[0].y = fmaf(p, v0v.y, oB[0].y);
                oB[0].z = fmaf(p, v0v.z, oB[0].z); oB[0].w = fmaf(p, v0v.w, oB[0].w);
                oB[1].x = fmaf(p, v1v.x, oB[1].x); oB[1].y = fmaf(p, v1v.y, oB[1].y);
                oB[1].z = fmaf(p, v1v.z, oB[1].z); oB[1].w = fmaf(p, v1v.w, oB[1].w);
                oB[2].x = fmaf(p, v2v.x, oB[2].x); oB[2].y = fmaf(p, v2v.y, oB[2].y);
                oB[2].z = fmaf(p, v2v.z, oB[2].z); oB[2].w = fmaf(p, v2v.w, oB[2].w);
                oB[3].x = fmaf(p, v3v.x, oB[3].x); oB[3].y = fmaf(p, v3v.y, oB[3].y);
                oB[3].z = fmaf(p, v3v.z, oB[3].z); oB[3].w = fmaf(p, v3v.w, oB[3].w);
            }
        }
        __syncthreads();   // all atomics done
        // flush this tile's amean and re-zero alds (each thread owns 4 slots)
        {
            const int r = t >> 4, c4 = t & 15;
            if (doA) {
                float4 w4 = make_float4(alds[0][r][c4 * 4], alds[0][r][c4 * 4 + 1],
                                        alds[0][r][c4 * 4 + 2], alds[0][r][c4 * 4 + 3]);
                *(float4*)&amean[((size_t)(b * NS + q0A + r)) * NS + k0 + c4 * 4] = w4;
                alds[0][r][c4 * 4] = 0.f; alds[0][r][c4 * 4 + 1] = 0.f;
                alds[0][r][c4 * 4 + 2] = 0.f; alds[0][r][c4 * 4 + 3] = 0.f;
            }
            if (doB) {
                float4 w4 = make_float4(alds[1][r][c4 * 4], alds[1][r][c4 * 4 + 1],
                                        alds[1][r][c4 * 4 + 2], alds[1][r][c4 * 4 + 3]);
                *(float4*)&amean[((size_t)(b * NS + q0B + r)) * NS + k0 + c4 * 4] = w4;
                alds[1][r][c4 * 4] = 0.f; alds[1][r][c4 * 4 + 1] = 0.f;
                alds[1][r][c4 * 4 + 2] = 0.f; alds[1][r][c4 * 4 + 3] = 0.f;
            }
        }
        // next iteration's post-stage __syncthreads orders these zeros
        // before the next tile's atomics.
    }

    // O reduce across kx quarters, lane kx==0 writes
    #pragma unroll
    for (int i = 0; i < 4; ++i) {
        oA[i].x += __shfl_xor(oA[i].x, 16, 64); oA[i].y += __shfl_xor(oA[i].y, 16, 64);
        oA[i].z += __shfl_xor(oA[i].z, 16, 64); oA[i].w += __shfl_xor(oA[i].w, 16, 64);
        oA[i].x += __shfl_xor(oA[i].x, 32, 64); oA[i].y += __shfl_xor(oA[i].y, 32, 64);
        oA[i].z += __shfl_xor(oA[i].z, 32, 64); oA[i].w += __shfl_xor(oA[i].w, 32, 64);
        oB[i].x += __shfl_xor(oB[i].x, 16, 64); oB[i].y += __shfl_xor(oB[i].y, 16, 64);
        oB[i].z += __shfl_xor(oB[i].z, 16, 64); oB[i].w += __shfl_xor(oB[i].w, 16, 64);
        oB[i].x += __shfl_xor(oB[i].x, 32, 64); oB[i].y += __shfl_xor(oB[i].y, 32, 64);
        oB[i].z += __shfl_xor(oB[i].z, 32, 64); oB[i].w += __shfl_xor(oB[i].w, 32, 64);
    }
    if (kx == 0) {
        #pragma unroll
        for (int i = 0; i < 4; ++i) {
            *(float4*)&out[((size_t)(b * NS + qrowA)) * NHID + h * 16 + i * 4] = oA[i];
            *(float4*)&out[((size_t)(b * NS + qrowB)) * NHID + h * 16 + i * 4] = oB[i];
        }
    }

    // zero-fill amean beyond processed tiles for both q-tiles
    const float4 z4 = make_float4(0.f, 0.f, 0.f, 0.f);
    {
        const int kzA = ntA << 6;
        const int nzA = (NS - kzA) >> 2;
        for (int r = 0; r < 16; ++r)
            for (int c4 = t; c4 < nzA; c4 += 256)
                *(float4*)&amean[((size_t)(b * NS + q0A + r)) * NS + kzA + c4 * 4] = z4;
        const int kzB = ntB << 6;
        const int nzB = (NS - kzB) >> 2;
        for (int r = 0; r < 16; ++r)
            for (int c4 = t; c4 < nzB; c4 += 256)
                *(float4*)&amean[((size_t)(b * NS + q0B + r)) * NS + kzB + c4 * 4] = z4;
    }
}

// ---------------------------------------------------------------------------
// Kernel 3: residual + LN1 + FFN(GELU exact) + residual + LN2 (unchanged).
// ---------------------------------------------------------------------------
__device__ __forceinline__ float wsum(float v) {
    #pragma unroll
    for (int o = 32; o > 0; o >>= 1) v += __shfl_xor(v, o, 64);
    return v;
}

__global__ __launch_bounds__(256) void ffn_kernel(
    const float* __restrict__ x, const float* __restrict__ aout,
    const float* __restrict__ W1, const float* __restrict__ b1,
    const float* __restrict__ W2, const float* __restrict__ b2,
    const float* __restrict__ g1, const float* __restrict__ be1,
    const float* __restrict__ g2, const float* __restrict__ be2,
    float* __restrict__ y)
{
    __shared__ float w1t[64][65], w2t[64][65];
    __shared__ float n1sh[4][64], h1sh[4][64];
    int t = threadIdx.x;
    for (int i = t; i < 4096; i += 256) {
        int c = i >> 6, j = i & 63;
        w1t[j][c] = W1[i];
        w2t[j][c] = W2[i];
    }
    __syncthreads();
    int wv = t >> 6, d = t & 63;
    size_t row = (size_t)blockIdx.x * 4 + wv;

    float o1 = x[row * 64 + d] + aout[row * 64 + d];
    float mu = wsum(o1) * (1.f / 64.f);
    float diff = o1 - mu;
    float var = wsum(diff * diff) * (1.f / 64.f);
    float n1 = diff * rsqrtf(var + LN_EPS) * g1[d] + be1[d];
    n1sh[wv][d] = n1;
    __syncthreads();
    float acc = b1[d];
    #pragma unroll
    for (int j = 0; j < 64; ++j) acc = fmaf(n1sh[wv][j], w1t[j][d], acc);
    float ge = 0.5f * acc * (1.f + erff(acc * 0.70710678118654752f));
    h1sh[wv][d] = ge;
    __syncthreads();
    float acc2 = b2[d];
    #pragma unroll
    for (int j = 0; j < 64; ++j) acc2 = fmaf(h1sh[wv][j], w2t[j][d], acc2);
    float z = n1 + acc2;
    float mu2 = wsum(z) * (1.f / 64.f);
    float d2 = z - mu2;
    float var2 = wsum(d2 * d2) * (1.f / 64.f);
    float yv = d2 * rsqrtf(var2 + LN_EPS) * g2[d] + be2[d];
    y[row * 64 + d] = yv;
}

// ---------------------------------------------------------------------------
extern "C" void kernel_launch(void* const* d_in, const int* in_sizes, int n_in,
                              void* d_out, int out_size, void* d_ws, size_t ws_size,
                              hipStream_t stream) {
    const float* x   = (const float*)d_in[0];
    const int* lengths = (const int*)d_in[1];
    const float* Wq  = (const float*)d_in[3];
    const float* bq  = (const float*)d_in[4];
    const float* Wk  = (const float*)d_in[5];
    const float* bk  = (const float*)d_in[6];
    const float* Wv  = (const float*)d_in[7];
    const float* bv  = (const float*)d_in[8];
    const float* W1  = (const float*)d_in[9];
    const float* b1  = (const float*)d_in[10];
    const float* W2  = (const float*)d_in[11];
    const float* b2  = (const float*)d_in[12];
    const float* g1  = (const float*)d_in[13];
    const float* be1 = (const float*)d_in[14];
    const float* g2  = (const float*)d_in[15];
    const float* be2 = (const float*)d_in[16];

    float* y     = (float*)d_out;                       // [B,S,64]
    float* amean = y + (size_t)NB * NS * NHID;          // [B,S,S]

    float* qw    = (float*)d_ws;                        // [B,NH,S,DH]
    float* kw    = qw + (size_t)NB * NHEADS * NS * NDH;
    float* vw    = kw + (size_t)NB * NHEADS * NS * NDH;
    float* aoutw = vw + (size_t)NB * NHEADS * NS * NDH; // [B,S,64]

    hipLaunchKernelGGL(qkv_kernel, dim3(NB * NS / 32), dim3(256), 0, stream,
                       x, Wq, bq, Wk, bk, Wv, bv, qw, kw, vw);
    hipLaunchKernelGGL(attn6_kernel, dim3(32, NB), dim3(256), 0, stream,
                       qw, kw, vw, lengths, amean, aoutw);
    hipLaunchKernelGGL(ffn_kernel, dim3(NB * NS / 4), dim3(256), 0, stream,
                       x, aoutw, W1, b1, W2, b2, g1, be1, g2, be2, y);
}

// Round 8
// 96.811 us; speedup vs baseline: 6.7639x; 3.3269x over previous
//
#include <hip/hip_runtime.h>

#define NB 16
#define NS 1024
#define NHID 64
#define NHEADS 4
#define NDH 16
#define LN_EPS 1e-5f

using v4h  = __attribute__((ext_vector_type(4))) _Float16;
using v8h  = __attribute__((ext_vector_type(8))) _Float16;
using v4f  = __attribute__((ext_vector_type(4))) float;

// ---------------------------------------------------------------------------
// Kernel 1: QKV projection -> f16 outputs: qh/kh [B,NH,S,16], vt [B,NH,16,S].
// Compute identical to prior rounds (fp32, LDS-transposed weights); outputs
// staged through LDS (q,k) or written directly (v, row-contiguous in s).
// ---------------------------------------------------------------------------
__global__ __launch_bounds__(256) void qkv_kernel(
    const float* __restrict__ x,
    const float* __restrict__ Wq, const float* __restrict__ bq,
    const float* __restrict__ Wk, const float* __restrict__ bk,
    const float* __restrict__ Wv, const float* __restrict__ bv,
    _Float16* __restrict__ qh, _Float16* __restrict__ kh,
    _Float16* __restrict__ vt)
{
    __shared__ float wqt[64][65], wkt[64][65], wvt[64][65];
    __shared__ float xs[32][64];
    __shared__ float stq[32][65], stk[32][65];
    int t = threadIdx.x;
    int row0 = blockIdx.x * 32;
    for (int i = t; i < 4096; i += 256) {
        int c = i >> 6, j = i & 63;
        wqt[j][c] = Wq[i];
        wkt[j][c] = Wk[i];
        wvt[j][c] = Wv[i];
    }
    for (int i = t; i < 2048; i += 256) {
        xs[i >> 6][i & 63] = x[(size_t)row0 * 64 + i];
    }
    __syncthreads();
    const int c = t & 63, rq = t >> 6;
    const int h = c >> 4, d = c & 15;
    const int b_ = row0 >> 10;          // 32 | 1024 -> block within one batch
    const int s0 = row0 & 1023;
    float bqv = bq[c], bkv = bk[c], bvv = bv[c];
    float av8[8];
    for (int rr = 0; rr < 8; ++rr) {
        int r = rq * 8 + rr;
        float aq = bqv, ak = bkv, av = bvv;
        #pragma unroll
        for (int j = 0; j < 64; ++j) {
            float xv = xs[r][j];
            aq = fmaf(xv, wqt[j][c], aq);
            ak = fmaf(xv, wkt[j][c], ak);
            av = fmaf(xv, wvt[j][c], av);
        }
        stq[r][c] = aq; stk[r][c] = ak; av8[rr] = av;
    }
    // vt: fixed (h,d), 8 consecutive s -> one 16B write
    {
        v8h v8;
        #pragma unroll
        for (int i = 0; i < 8; ++i) v8[i] = (_Float16)av8[i];
        *(v8h*)&vt[(((size_t)(b_ * NHEADS + h)) * NDH + d) * NS + s0 + rq * 8] = v8;
    }
    __syncthreads();
    // qh/kh: thread u -> row r=u>>3, cols c8..c8+7 -> one 16B write each
    {
        const int r = t >> 3, c8 = (t & 7) * 8;
        v8h q8, k8;
        #pragma unroll
        for (int i = 0; i < 8; ++i) {
            q8[i] = (_Float16)stq[r][c8 + i];
            k8[i] = (_Float16)stk[r][c8 + i];
        }
        const int hh = c8 >> 4, dd = c8 & 15;
        size_t o = (((size_t)(b_ * NHEADS + hh)) * NS + s0 + r) * NDH + dd;
        *(v8h*)&qh[o] = q8;
        *(v8h*)&kh[o] = k8;
    }
}

// ---------------------------------------------------------------------------
// Kernel 2 (attn7): MFMA attention. Block=(pair pr, batch b); wave = head.
// Sides A=q-tile pr, B=q-tile 63-pr (16 rows each), fused lockstep k-sweep.
// S^T = mfma(A=Kfrag, B=Qfrag): lane holds S[q=l&15][kcol=4*(l>>4)+i] which
// is EXACTLY the A-operand layout for PV mfma(P, Vfrag) -> softmax fully
// in-register, no transposes. Q/K/V frags loaded 8B/lane from global (L2).
// LDS only for cross-head amean sum (plain writes, no atomics).
// ---------------------------------------------------------------------------
__global__ __launch_bounds__(256, 4) void attn7_kernel(
    const _Float16* __restrict__ qh, const _Float16* __restrict__ kh,
    const _Float16* __restrict__ vt, const int* __restrict__ lengths,
    float* __restrict__ amean,   // [B,S,S]
    float* __restrict__ out)     // [B,S,64]
{
    __shared__ float Plds[2][NHEADS][16][68];

    const int t = threadIdx.x;
    const int h = t >> 6, l = t & 63;
    const int g = l >> 4, n16 = l & 15;
    const int pr = blockIdx.x, b = blockIdx.y;
    const int len = lengths[b];
    const int q0A = pr << 4, q0B = (63 - pr) << 4;
    const int qA_ = q0A + n16, qB_ = q0B + n16;  // lane's q-row (frag n pos)

    const size_t hbase = ((size_t)(b * NHEADS + h)) * NS;
    const v4h QA = *(const v4h*)&qh[(hbase + qA_) * NDH + 4 * g];
    const v4h QB = *(const v4h*)&qh[(hbase + qB_) * NDH + 4 * g];

    const int nkA = (len <= q0A) ? 0 : min(q0A + 16, len);
    const int nkB = (len <= q0B) ? 0 : min(q0B + 16, len);
    const int ntA = (nkA + 63) >> 6, ntB = (nkB + 63) >> 6;
    const int ntM = max(ntA, ntB);
    const v4f z4v = {0.f, 0.f, 0.f, 0.f};

    // ---------------- pass 1: Z ----------------
    float ZA = 0.f, ZB = 0.f;
    for (int ks = 0; ks < ntM * 64; ks += 16) {
        if (ks >= nkA && ks >= nkB) continue;
        const v4h K = *(const v4h*)&kh[(hbase + ks + n16) * NDH + 4 * g];
        if (ks < nkA) {
            v4f st = __builtin_amdgcn_mfma_f32_16x16x16f16(K, QA, z4v, 0, 0, 0);
            #pragma unroll
            for (int i = 0; i < 4; ++i) {
                int kg = ks + 4 * g + i;
                ZA += ((qA_ < len) && (kg <= qA_)) ? __expf(st[i] * 0.125f) : 0.f;
            }
        }
        if (ks < nkB) {
            v4f st = __builtin_amdgcn_mfma_f32_16x16x16f16(K, QB, z4v, 0, 0, 0);
            #pragma unroll
            for (int i = 0; i < 4; ++i) {
                int kg = ks + 4 * g + i;
                ZB += ((qB_ < len) && (kg <= qB_)) ? __expf(st[i] * 0.125f) : 0.f;
            }
        }
    }
    ZA += __shfl_xor(ZA, 16, 64); ZA += __shfl_xor(ZA, 32, 64);
    ZB += __shfl_xor(ZB, 16, 64); ZB += __shfl_xor(ZB, 32, 64);
    const float izA = (ZA > 0.f) ? 1.f / ZA : 0.f;
    const float izB = (ZB > 0.f) ? 1.f / ZB : 0.f;

    // ---------------- pass 2: P, amean, PV ----------------
    v4f oA = z4v, oB = z4v;
    for (int tile = 0; tile < ntM; ++tile) {
        const int k0 = tile << 6;
        #pragma unroll
        for (int sub = 0; sub < 4; ++sub) {
            const int ks = k0 + sub * 16;
            const v4h K = *(const v4h*)&kh[(hbase + ks + n16) * NDH + 4 * g];
            const v4h V = *(const v4h*)&vt[(((size_t)(b * NHEADS + h)) * NDH + n16) * NS + ks + 4 * g];
            v4f pA = z4v, pB = z4v;
            if (ks < nkA) {
                v4f st = __builtin_amdgcn_mfma_f32_16x16x16f16(K, QA, z4v, 0, 0, 0);
                #pragma unroll
                for (int i = 0; i < 4; ++i) {
                    int kg = ks + 4 * g + i;
                    pA[i] = ((qA_ < len) && (kg <= qA_)) ? __expf(st[i] * 0.125f) * izA : 0.f;
                }
                v4h ph = {(_Float16)pA[0], (_Float16)pA[1], (_Float16)pA[2], (_Float16)pA[3]};
                oA = __builtin_amdgcn_mfma_f32_16x16x16f16(ph, V, oA, 0, 0, 0);
            }
            if (ks < nkB) {
                v4f st = __builtin_amdgcn_mfma_f32_16x16x16f16(K, QB, z4v, 0, 0, 0);
                #pragma unroll
                for (int i = 0; i < 4; ++i) {
                    int kg = ks + 4 * g + i;
                    pB[i] = ((qB_ < len) && (kg <= qB_)) ? __expf(st[i] * 0.125f) * izB : 0.f;
                }
                v4h ph = {(_Float16)pB[0], (_Float16)pB[1], (_Float16)pB[2], (_Float16)pB[3]};
                oB = __builtin_amdgcn_mfma_f32_16x16x16f16(ph, V, oB, 0, 0, 0);
            }
            *(float4*)&Plds[0][h][n16][sub * 16 + 4 * g] =
                make_float4(0.25f * pA[0], 0.25f * pA[1], 0.25f * pA[2], 0.25f * pA[3]);
            *(float4*)&Plds[1][h][n16][sub * 16 + 4 * g] =
                make_float4(0.25f * pB[0], 0.25f * pB[1], 0.25f * pB[2], 0.25f * pB[3]);
        }
        __syncthreads();
        {
            const int r = t >> 4, c4 = (t & 15) * 4;
            if (tile < ntA) {
                float4 a0 = *(float4*)&Plds[0][0][r][c4];
                float4 a1 = *(float4*)&Plds[0][1][r][c4];
                float4 a2 = *(float4*)&Plds[0][2][r][c4];
                float4 a3 = *(float4*)&Plds[0][3][r][c4];
                float4 w = make_float4(a0.x + a1.x + a2.x + a3.x,
                                       a0.y + a1.y + a2.y + a3.y,
                                       a0.z + a1.z + a2.z + a3.z,
                                       a0.w + a1.w + a2.w + a3.w);
                *(float4*)&amean[((size_t)(b * NS + q0A + r)) * NS + k0 + c4] = w;
            }
            if (tile < ntB) {
                float4 a0 = *(float4*)&Plds[1][0][r][c4];
                float4 a1 = *(float4*)&Plds[1][1][r][c4];
                float4 a2 = *(float4*)&Plds[1][2][r][c4];
                float4 a3 = *(float4*)&Plds[1][3][r][c4];
                float4 w = make_float4(a0.x + a1.x + a2.x + a3.x,
                                       a0.y + a1.y + a2.y + a3.y,
                                       a0.z + a1.z + a2.z + a3.z,
                                       a0.w + a1.w + a2.w + a3.w);
                *(float4*)&amean[((size_t)(b * NS + q0B + r)) * NS + k0 + c4] = w;
            }
        }
        __syncthreads();
    }

    // O write: D layout -> row q0+4g+i, col h*16+n16
    #pragma unroll
    for (int i = 0; i < 4; ++i) {
        out[((size_t)(b * NS) + q0A + 4 * g + i) * NHID + h * 16 + n16] = oA[i];
        out[((size_t)(b * NS) + q0B + 4 * g + i) * NHID + h * 16 + n16] = oB[i];
    }

    // zero-fill amean beyond processed tiles for both sides
    const float4 zf = make_float4(0.f, 0.f, 0.f, 0.f);
    {
        const int kzA = ntA << 6;
        const int nzA = (NS - kzA) >> 2;
        for (int r = 0; r < 16; ++r)
            for (int c4 = t; c4 < nzA; c4 += 256)
                *(float4*)&amean[((size_t)(b * NS + q0A + r)) * NS + kzA + c4 * 4] = zf;
        const int kzB = ntB << 6;
        const int nzB = (NS - kzB) >> 2;
        for (int r = 0; r < 16; ++r)
            for (int c4 = t; c4 < nzB; c4 += 256)
                *(float4*)&amean[((size_t)(b * NS + q0B + r)) * NS + kzB + c4 * 4] = zf;
    }
}

// ---------------------------------------------------------------------------
// Kernel 3: residual + LN1 + FFN(GELU exact) + residual + LN2 (unchanged).
// ---------------------------------------------------------------------------
__device__ __forceinline__ float wsum(float v) {
    #pragma unroll
    for (int o = 32; o > 0; o >>= 1) v += __shfl_xor(v, o, 64);
    return v;
}

__global__ __launch_bounds__(256) void ffn_kernel(
    const float* __restrict__ x, const float* __restrict__ aout,
    const float* __restrict__ W1, const float* __restrict__ b1,
    const float* __restrict__ W2, const float* __restrict__ b2,
    const float* __restrict__ g1, const float* __restrict__ be1,
    const float* __restrict__ g2, const float* __restrict__ be2,
    float* __restrict__ y)
{
    __shared__ float w1t[64][65], w2t[64][65];
    __shared__ float n1sh[4][64], h1sh[4][64];
    int t = threadIdx.x;
    for (int i = t; i < 4096; i += 256) {
        int c = i >> 6, j = i & 63;
        w1t[j][c] = W1[i];
        w2t[j][c] = W2[i];
    }
    __syncthreads();
    int wv = t >> 6, d = t & 63;
    size_t row = (size_t)blockIdx.x * 4 + wv;

    float o1 = x[row * 64 + d] + aout[row * 64 + d];
    float mu = wsum(o1) * (1.f / 64.f);
    float diff = o1 - mu;
    float var = wsum(diff * diff) * (1.f / 64.f);
    float n1 = diff * rsqrtf(var + LN_EPS) * g1[d] + be1[d];
    n1sh[wv][d] = n1;
    __syncthreads();
    float acc = b1[d];
    #pragma unroll
    for (int j = 0; j < 64; ++j) acc = fmaf(n1sh[wv][j], w1t[j][d], acc);
    float ge = 0.5f * acc * (1.f + erff(acc * 0.70710678118654752f));
    h1sh[wv][d] = ge;
    __syncthreads();
    float acc2 = b2[d];
    #pragma unroll
    for (int j = 0; j < 64; ++j) acc2 = fmaf(h1sh[wv][j], w2t[j][d], acc2);
    float z = n1 + acc2;
    float mu2 = wsum(z) * (1.f / 64.f);
    float d2 = z - mu2;
    float var2 = wsum(d2 * d2) * (1.f / 64.f);
    float yv = d2 * rsqrtf(var2 + LN_EPS) * g2[d] + be2[d];
    y[row * 64 + d] = yv;
}

// ---------------------------------------------------------------------------
extern "C" void kernel_launch(void* const* d_in, const int* in_sizes, int n_in,
                              void* d_out, int out_size, void* d_ws, size_t ws_size,
                              hipStream_t stream) {
    const float* x   = (const float*)d_in[0];
    const int* lengths = (const int*)d_in[1];
    const float* Wq  = (const float*)d_in[3];
    const float* bq  = (const float*)d_in[4];
    const float* Wk  = (const float*)d_in[5];
    const float* bk  = (const float*)d_in[6];
    const float* Wv  = (const float*)d_in[7];
    const float* bv  = (const float*)d_in[8];
    const float* W1  = (const float*)d_in[9];
    const float* b1  = (const float*)d_in[10];
    const float* W2  = (const float*)d_in[11];
    const float* b2  = (const float*)d_in[12];
    const float* g1  = (const float*)d_in[13];
    const float* be1 = (const float*)d_in[14];
    const float* g2  = (const float*)d_in[15];
    const float* be2 = (const float*)d_in[16];

    float* y     = (float*)d_out;                       // [B,S,64]
    float* amean = y + (size_t)NB * NS * NHID;          // [B,S,S]

    const size_t nqkv = (size_t)NB * NHEADS * NS * NDH; // 1,048,576 elems
    _Float16* qhw = (_Float16*)d_ws;                    // f16 [B,NH,S,16]
    _Float16* khw = qhw + nqkv;
    _Float16* vtw = khw + nqkv;                         // f16 [B,NH,16,S]
    float* aoutw  = (float*)(vtw + nqkv);               // fp32 [B,S,64]

    hipLaunchKernelGGL(qkv_kernel, dim3(NB * NS / 32), dim3(256), 0, stream,
                       x, Wq, bq, Wk, bk, Wv, bv, qhw, khw, vtw);
    hipLaunchKernelGGL(attn7_kernel, dim3(32, NB), dim3(256), 0, stream,
                       qhw, khw, vtw, lengths, amean, aoutw);
    hipLaunchKernelGGL(ffn_kernel, dim3(NB * NS / 4), dim3(256), 0, stream,
                       x, aoutw, W1, b1, W2, b2, g1, be1, g2, be2, y);
}

// Round 9
// 77.851 us; speedup vs baseline: 8.4112x; 1.2435x over previous
//
#include <hip/hip_runtime.h>

#define NB 16
#define NS 1024
#define NHID 64
#define NHEADS 4
#define NDH 16
#define LN_EPS 1e-5f

using v4h  = __attribute__((ext_vector_type(4))) _Float16;
using v8h  = __attribute__((ext_vector_type(8))) _Float16;
using v4f  = __attribute__((ext_vector_type(4))) float;

// ---------------------------------------------------------------------------
// Kernel 1: QKV projection -> f16: qh/kh [B,NH,S,16], vt [B,NH,16,S]. Unchanged.
// ---------------------------------------------------------------------------
__global__ __launch_bounds__(256) void qkv_kernel(
    const float* __restrict__ x,
    const float* __restrict__ Wq, const float* __restrict__ bq,
    const float* __restrict__ Wk, const float* __restrict__ bk,
    const float* __restrict__ Wv, const float* __restrict__ bv,
    _Float16* __restrict__ qh, _Float16* __restrict__ kh,
    _Float16* __restrict__ vt)
{
    __shared__ float wqt[64][65], wkt[64][65], wvt[64][65];
    __shared__ float xs[32][64];
    __shared__ float stq[32][65], stk[32][65];
    int t = threadIdx.x;
    int row0 = blockIdx.x * 32;
    for (int i = t; i < 4096; i += 256) {
        int c = i >> 6, j = i & 63;
        wqt[j][c] = Wq[i];
        wkt[j][c] = Wk[i];
        wvt[j][c] = Wv[i];
    }
    for (int i = t; i < 2048; i += 256) {
        xs[i >> 6][i & 63] = x[(size_t)row0 * 64 + i];
    }
    __syncthreads();
    const int c = t & 63, rq = t >> 6;
    const int h = c >> 4, d = c & 15;
    const int b_ = row0 >> 10;
    const int s0 = row0 & 1023;
    float bqv = bq[c], bkv = bk[c], bvv = bv[c];
    float av8[8];
    for (int rr = 0; rr < 8; ++rr) {
        int r = rq * 8 + rr;
        float aq = bqv, ak = bkv, av = bvv;
        #pragma unroll
        for (int j = 0; j < 64; ++j) {
            float xv = xs[r][j];
            aq = fmaf(xv, wqt[j][c], aq);
            ak = fmaf(xv, wkt[j][c], ak);
            av = fmaf(xv, wvt[j][c], av);
        }
        stq[r][c] = aq; stk[r][c] = ak; av8[rr] = av;
    }
    {
        v8h v8;
        #pragma unroll
        for (int i = 0; i < 8; ++i) v8[i] = (_Float16)av8[i];
        *(v8h*)&vt[(((size_t)(b_ * NHEADS + h)) * NDH + d) * NS + s0 + rq * 8] = v8;
    }
    __syncthreads();
    {
        const int r = t >> 3, c8 = (t & 7) * 8;
        v8h q8, k8;
        #pragma unroll
        for (int i = 0; i < 8; ++i) {
            q8[i] = (_Float16)stq[r][c8 + i];
            k8[i] = (_Float16)stk[r][c8 + i];
        }
        const int hh = c8 >> 4, dd = c8 & 15;
        size_t o = (((size_t)(b_ * NHEADS + hh)) * NS + s0 + r) * NDH + dd;
        *(v8h*)&qh[o] = q8;
        *(v8h*)&kh[o] = k8;
    }
}

// ---------------------------------------------------------------------------
// Kernel 2 (attn8): attn7's MFMA structure at 16 waves/block (1024 thr).
// Wave = (head h = wv&3, k-slot kq = wv>>2): each wave handles the 16-k
// sub-tile kq of every 64-k tile. 512 blocks x 16 waves = 8192 waves =
// 100% machine wave capacity (attn7: 2 blk/CU = 25% cap, measured 10%).
// Z: in-wave shfl + cross-kq via zlds. O: partial per wave, cross-kq
// reduce via obuf (aliases Plds after last amean flush).
// ---------------------------------------------------------------------------
__global__ __launch_bounds__(1024, 8) void attn8_kernel(
    const _Float16* __restrict__ qh, const _Float16* __restrict__ kh,
    const _Float16* __restrict__ vt, const int* __restrict__ lengths,
    float* __restrict__ amean,   // [B,S,S]
    float* __restrict__ out)     // [B,S,64]
{
    __shared__ float Plds[2][NHEADS][16][68];   // 34816 B (also obuf at end)
    __shared__ float zlds[4][NHEADS][16][2];    // 2 KB

    const int t = threadIdx.x;
    const int wv = t >> 6;
    const int h  = wv & 3;
    const int kq = wv >> 2;
    const int l  = t & 63;
    const int g = l >> 4, n16 = l & 15;
    const int pr = blockIdx.x, b = blockIdx.y;
    const int len = lengths[b];
    const int q0A = pr << 4, q0B = (63 - pr) << 4;
    const int qA_ = q0A + n16, qB_ = q0B + n16;
    const bool qvA = qA_ < len, qvB = qB_ < len;

    const size_t hbase = ((size_t)(b * NHEADS + h)) * NS;
    const v4h QA = *(const v4h*)&qh[(hbase + qA_) * NDH + 4 * g];
    const v4h QB = *(const v4h*)&qh[(hbase + qB_) * NDH + 4 * g];

    const int nkA = (len <= q0A) ? 0 : min(q0A + 16, len);
    const int nkB = (len <= q0B) ? 0 : min(q0B + 16, len);
    const int ntA = (nkA + 63) >> 6, ntB = (nkB + 63) >> 6;
    const int ntM = max(ntA, ntB);
    const v4f z4v = {0.f, 0.f, 0.f, 0.f};

    // ---------------- pass 1: Z ----------------
    float ZA = 0.f, ZB = 0.f;
    for (int tile = 0; tile < ntM; ++tile) {
        const int ks = (tile << 6) + (kq << 4);
        if (ks >= nkA && ks >= nkB) continue;
        const v4h K = *(const v4h*)&kh[(hbase + ks + n16) * NDH + 4 * g];
        if (ks < nkA) {
            v4f st = __builtin_amdgcn_mfma_f32_16x16x16f16(K, QA, z4v, 0, 0, 0);
            #pragma unroll
            for (int i = 0; i < 4; ++i) {
                int kg = ks + 4 * g + i;
                ZA += (qvA && kg <= qA_) ? __expf(st[i] * 0.125f) : 0.f;
            }
        }
        if (ks < nkB) {
            v4f st = __builtin_amdgcn_mfma_f32_16x16x16f16(K, QB, z4v, 0, 0, 0);
            #pragma unroll
            for (int i = 0; i < 4; ++i) {
                int kg = ks + 4 * g + i;
                ZB += (qvB && kg <= qB_) ? __expf(st[i] * 0.125f) : 0.f;
            }
        }
    }
    ZA += __shfl_xor(ZA, 16, 64); ZA += __shfl_xor(ZA, 32, 64);
    ZB += __shfl_xor(ZB, 16, 64); ZB += __shfl_xor(ZB, 32, 64);
    if (l < 16) {
        zlds[kq][h][n16][0] = ZA;
        zlds[kq][h][n16][1] = ZB;
    }
    __syncthreads();
    const float ztA = zlds[0][h][n16][0] + zlds[1][h][n16][0]
                    + zlds[2][h][n16][0] + zlds[3][h][n16][0];
    const float ztB = zlds[0][h][n16][1] + zlds[1][h][n16][1]
                    + zlds[2][h][n16][1] + zlds[3][h][n16][1];
    const float izA = (ztA > 0.f) ? 1.f / ztA : 0.f;
    const float izB = (ztB > 0.f) ? 1.f / ztB : 0.f;

    // ---------------- pass 2: P, amean, PV ----------------
    v4f oA = z4v, oB = z4v;
    for (int tile = 0; tile < ntM; ++tile) {
        const int k0 = tile << 6;
        const int ks = k0 + (kq << 4);
        const bool doA = tile < ntA, doB = tile < ntB;
        v4f pA = z4v, pB = z4v;
        if (ks < nkA || ks < nkB) {
            const v4h K = *(const v4h*)&kh[(hbase + ks + n16) * NDH + 4 * g];
            const v4h V = *(const v4h*)&vt[(((size_t)(b * NHEADS + h)) * NDH + n16) * NS + ks + 4 * g];
            if (ks < nkA) {
                v4f st = __builtin_amdgcn_mfma_f32_16x16x16f16(K, QA, z4v, 0, 0, 0);
                #pragma unroll
                for (int i = 0; i < 4; ++i) {
                    int kg = ks + 4 * g + i;
                    pA[i] = (qvA && kg <= qA_) ? __expf(st[i] * 0.125f) * izA : 0.f;
                }
                v4h ph = {(_Float16)pA[0], (_Float16)pA[1], (_Float16)pA[2], (_Float16)pA[3]};
                oA = __builtin_amdgcn_mfma_f32_16x16x16f16(ph, V, oA, 0, 0, 0);
            }
            if (ks < nkB) {
                v4f st = __builtin_amdgcn_mfma_f32_16x16x16f16(K, QB, z4v, 0, 0, 0);
                #pragma unroll
                for (int i = 0; i < 4; ++i) {
                    int kg = ks + 4 * g + i;
                    pB[i] = (qvB && kg <= qB_) ? __expf(st[i] * 0.125f) * izB : 0.f;
                }
                v4h ph = {(_Float16)pB[0], (_Float16)pB[1], (_Float16)pB[2], (_Float16)pB[3]};
                oB = __builtin_amdgcn_mfma_f32_16x16x16f16(ph, V, oB, 0, 0, 0);
            }
        }
        const int pc = (kq << 4) + 4 * g;
        *(float4*)&Plds[0][h][n16][pc] =
            make_float4(0.25f * pA[0], 0.25f * pA[1], 0.25f * pA[2], 0.25f * pA[3]);
        *(float4*)&Plds[1][h][n16][pc] =
            make_float4(0.25f * pB[0], 0.25f * pB[1], 0.25f * pB[2], 0.25f * pB[3]);
        __syncthreads();
        if (t < 512) {
            const int sid = t >> 8, r = (t >> 4) & 15, c4 = (t & 15) * 4;
            if (sid == 0 ? doA : doB) {
                float4 a0 = *(float4*)&Plds[sid][0][r][c4];
                float4 a1 = *(float4*)&Plds[sid][1][r][c4];
                float4 a2 = *(float4*)&Plds[sid][2][r][c4];
                float4 a3 = *(float4*)&Plds[sid][3][r][c4];
                float4 w = make_float4(a0.x + a1.x + a2.x + a3.x,
                                       a0.y + a1.y + a2.y + a3.y,
                                       a0.z + a1.z + a2.z + a3.z,
                                       a0.w + a1.w + a2.w + a3.w);
                const int q0 = sid == 0 ? q0A : q0B;
                *(float4*)&amean[((size_t)(b * NS + q0 + r)) * NS + k0 + c4] = w;
            }
        }
        __syncthreads();
    }

    // ---------------- O cross-kq reduce (obuf aliases Plds) ----------------
    float* obuf = (float*)Plds;          // [16][64][8] floats = 32 KB
    {
        float* p = &obuf[(wv * 64 + l) * 8];
        p[0] = oA[0]; p[1] = oA[1]; p[2] = oA[2]; p[3] = oA[3];
        p[4] = oB[0]; p[5] = oB[1]; p[6] = oB[2]; p[7] = oB[3];
    }
    __syncthreads();
    if (kq == 0) {
        #pragma unroll
        for (int kq2 = 1; kq2 < 4; ++kq2) {
            const float* p = &obuf[(((h + 4 * kq2) * 64) + l) * 8];
            oA[0] += p[0]; oA[1] += p[1]; oA[2] += p[2]; oA[3] += p[3];
            oB[0] += p[4]; oB[1] += p[5]; oB[2] += p[6]; oB[3] += p[7];
        }
        #pragma unroll
        for (int i = 0; i < 4; ++i) {
            out[((size_t)(b * NS) + q0A + 4 * g + i) * NHID + h * 16 + n16] = oA[i];
            out[((size_t)(b * NS) + q0B + 4 * g + i) * NHID + h * 16 + n16] = oB[i];
        }
    }

    // ---------------- amean zero-fill beyond processed tiles ----------------
    const float4 zf = make_float4(0.f, 0.f, 0.f, 0.f);
    {
        const int kzA = ntA << 6;
        const int nzA = (NS - kzA) >> 2;
        for (int r = 0; r < 16; ++r)
            for (int c4 = t; c4 < nzA; c4 += 1024)
                *(float4*)&amean[((size_t)(b * NS + q0A + r)) * NS + kzA + c4 * 4] = zf;
        const int kzB = ntB << 6;
        const int nzB = (NS - kzB) >> 2;
        for (int r = 0; r < 16; ++r)
            for (int c4 = t; c4 < nzB; c4 += 1024)
                *(float4*)&amean[((size_t)(b * NS + q0B + r)) * NS + kzB + c4 * 4] = zf;
    }
}

// ---------------------------------------------------------------------------
// Kernel 3: residual + LN1 + FFN(GELU exact) + residual + LN2 (unchanged).
// ---------------------------------------------------------------------------
__device__ __forceinline__ float wsum(float v) {
    #pragma unroll
    for (int o = 32; o > 0; o >>= 1) v += __shfl_xor(v, o, 64);
    return v;
}

__global__ __launch_bounds__(256) void ffn_kernel(
    const float* __restrict__ x, const float* __restrict__ aout,
    const float* __restrict__ W1, const float* __restrict__ b1,
    const float* __restrict__ W2, const float* __restrict__ b2,
    const float* __restrict__ g1, const float* __restrict__ be1,
    const float* __restrict__ g2, const float* __restrict__ be2,
    float* __restrict__ y)
{
    __shared__ float w1t[64][65], w2t[64][65];
    __shared__ float n1sh[4][64], h1sh[4][64];
    int t = threadIdx.x;
    for (int i = t; i < 4096; i += 256) {
        int c = i >> 6, j = i & 63;
        w1t[j][c] = W1[i];
        w2t[j][c] = W2[i];
    }
    __syncthreads();
    int wv = t >> 6, d = t & 63;
    size_t row = (size_t)blockIdx.x * 4 + wv;

    float o1 = x[row * 64 + d] + aout[row * 64 + d];
    float mu = wsum(o1) * (1.f / 64.f);
    float diff = o1 - mu;
    float var = wsum(diff * diff) * (1.f / 64.f);
    float n1 = diff * rsqrtf(var + LN_EPS) * g1[d] + be1[d];
    n1sh[wv][d] = n1;
    __syncthreads();
    float acc = b1[d];
    #pragma unroll
    for (int j = 0; j < 64; ++j) acc = fmaf(n1sh[wv][j], w1t[j][d], acc);
    float ge = 0.5f * acc * (1.f + erff(acc * 0.70710678118654752f));
    h1sh[wv][d] = ge;
    __syncthreads();
    float acc2 = b2[d];
    #pragma unroll
    for (int j = 0; j < 64; ++j) acc2 = fmaf(h1sh[wv][j], w2t[j][d], acc2);
    float z = n1 + acc2;
    float mu2 = wsum(z) * (1.f / 64.f);
    float d2 = z - mu2;
    float var2 = wsum(d2 * d2) * (1.f / 64.f);
    float yv = d2 * rsqrtf(var2 + LN_EPS) * g2[d] + be2[d];
    y[row * 64 + d] = yv;
}

// ---------------------------------------------------------------------------
extern "C" void kernel_launch(void* const* d_in, const int* in_sizes, int n_in,
                              void* d_out, int out_size, void* d_ws, size_t ws_size,
                              hipStream_t stream) {
    const float* x   = (const float*)d_in[0];
    const int* lengths = (const int*)d_in[1];
    const float* Wq  = (const float*)d_in[3];
    const float* bq  = (const float*)d_in[4];
    const float* Wk  = (const float*)d_in[5];
    const float* bk  = (const float*)d_in[6];
    const float* Wv  = (const float*)d_in[7];
    const float* bv  = (const float*)d_in[8];
    const float* W1  = (const float*)d_in[9];
    const float* b1  = (const float*)d_in[10];
    const float* W2  = (const float*)d_in[11];
    const float* b2  = (const float*)d_in[12];
    const float* g1  = (const float*)d_in[13];
    const float* be1 = (const float*)d_in[14];
    const float* g2  = (const float*)d_in[15];
    const float* be2 = (const float*)d_in[16];

    float* y     = (float*)d_out;                       // [B,S,64]
    float* amean = y + (size_t)NB * NS * NHID;          // [B,S,S]

    const size_t nqkv = (size_t)NB * NHEADS * NS * NDH; // 1,048,576 elems
    _Float16* qhw = (_Float16*)d_ws;                    // f16 [B,NH,S,16]
    _Float16* khw = qhw + nqkv;
    _Float16* vtw = khw + nqkv;                         // f16 [B,NH,16,S]
    float* aoutw  = (float*)(vtw + nqkv);               // fp32 [B,S,64]

    hipLaunchKernelGGL(qkv_kernel, dim3(NB * NS / 32), dim3(256), 0, stream,
                       x, Wq, bq, Wk, bk, Wv, bv, qhw, khw, vtw);
    hipLaunchKernelGGL(attn8_kernel, dim3(32, NB), dim3(1024), 0, stream,
                       qhw, khw, vtw, lengths, amean, aoutw);
    hipLaunchKernelGGL(ffn_kernel, dim3(NB * NS / 4), dim3(256), 0, stream,
                       x, aoutw, W1, b1, W2, b2, g1, be1, g2, be2, y);
}

// Round 10
// 66.763 us; speedup vs baseline: 9.8081x; 1.1661x over previous
//
#include <hip/hip_runtime.h>

#define NB 16
#define NS 1024
#define NHID 64
#define NHEADS 4
#define NDH 16
#define LN_EPS 1e-5f

using v4h  = __attribute__((ext_vector_type(4))) _Float16;
using v4f  = __attribute__((ext_vector_type(4))) float;

__device__ __forceinline__ v4h cvt4h(float4 a) {
    v4h r; r[0] = (_Float16)a.x; r[1] = (_Float16)a.y;
    r[2] = (_Float16)a.z; r[3] = (_Float16)a.w; return r;
}

// ---------------------------------------------------------------------------
// Kernel 1 (qkv_mfma): one wave per 16-row tile; no LDS, no barriers.
// out^T = W . x^T per 16-col block: A = W-frag (rows of W, contiguous),
// B = x^T-frag (lane holds x[row=l&15][j=4g+i]), D = lane holds
// out[row=l&15... n][c = mb*16+4g+i]. f16 in, f32 accum, f16 out.
// ---------------------------------------------------------------------------
__global__ __launch_bounds__(256) void qkv_mfma_kernel(
    const float* __restrict__ x,
    const float* __restrict__ Wq, const float* __restrict__ bq,
    const float* __restrict__ Wk, const float* __restrict__ bk,
    const float* __restrict__ Wv, const float* __restrict__ bv,
    _Float16* __restrict__ qh, _Float16* __restrict__ kh,
    _Float16* __restrict__ vt)
{
    const int t = threadIdx.x;
    const int w = t >> 6, l = t & 63;
    const int n16 = l & 15, g = l >> 4;
    const int rt = (int)blockIdx.x * 4 + w;
    const int srow0 = rt * 16;                 // tile's first global row
    const int b = srow0 >> 10, s0 = srow0 & 1023;
    const size_t sg = (size_t)srow0 + n16;     // this lane's B-frag row

    v4h xa[4];
    #pragma unroll
    for (int kb = 0; kb < 4; ++kb)
        xa[kb] = cvt4h(*(const float4*)&x[sg * 64 + kb * 16 + 4 * g]);

    #pragma unroll
    for (int m = 0; m < 3; ++m) {
        const float* W  = (m == 0) ? Wq : (m == 1) ? Wk : Wv;
        const float* bb = (m == 0) ? bq : (m == 1) ? bk : bv;
        #pragma unroll
        for (int mb = 0; mb < 4; ++mb) {
            const float4 bv4 = *(const float4*)&bb[mb * 16 + 4 * g];
            v4f acc = {bv4.x, bv4.y, bv4.z, bv4.w};
            #pragma unroll
            for (int kb = 0; kb < 4; ++kb) {
                v4h wf = cvt4h(*(const float4*)&W[(size_t)(mb * 16 + n16) * 64 + kb * 16 + 4 * g]);
                acc = __builtin_amdgcn_mfma_f32_16x16x16f16(wf, xa[kb], acc, 0, 0, 0);
            }
            const size_t hb = (size_t)(b * NHEADS + mb);
            if (m == 0) {
                v4h r = {(_Float16)acc[0], (_Float16)acc[1], (_Float16)acc[2], (_Float16)acc[3]};
                *(v4h*)&qh[(hb * NS + s0 + n16) * NDH + 4 * g] = r;
            } else if (m == 1) {
                v4h r = {(_Float16)acc[0], (_Float16)acc[1], (_Float16)acc[2], (_Float16)acc[3]};
                *(v4h*)&kh[(hb * NS + s0 + n16) * NDH + 4 * g] = r;
            } else {
                #pragma unroll
                for (int i = 0; i < 4; ++i)
                    vt[(hb * NDH + 4 * g + i) * NS + s0 + n16] = (_Float16)acc[i];
            }
        }
    }
}

// ---------------------------------------------------------------------------
// Kernel 2 (attn8): unchanged from round 9 (MFMA attention, 16 waves/block).
// ---------------------------------------------------------------------------
__global__ __launch_bounds__(1024, 8) void attn8_kernel(
    const _Float16* __restrict__ qh, const _Float16* __restrict__ kh,
    const _Float16* __restrict__ vt, const int* __restrict__ lengths,
    float* __restrict__ amean,   // [B,S,S]
    float* __restrict__ out)     // [B,S,64]
{
    __shared__ float Plds[2][NHEADS][16][68];
    __shared__ float zlds[4][NHEADS][16][2];

    const int t = threadIdx.x;
    const int wv = t >> 6;
    const int h  = wv & 3;
    const int kq = wv >> 2;
    const int l  = t & 63;
    const int g = l >> 4, n16 = l & 15;
    const int pr = blockIdx.x, b = blockIdx.y;
    const int len = lengths[b];
    const int q0A = pr << 4, q0B = (63 - pr) << 4;
    const int qA_ = q0A + n16, qB_ = q0B + n16;
    const bool qvA = qA_ < len, qvB = qB_ < len;

    const size_t hbase = ((size_t)(b * NHEADS + h)) * NS;
    const v4h QA = *(const v4h*)&qh[(hbase + qA_) * NDH + 4 * g];
    const v4h QB = *(const v4h*)&qh[(hbase + qB_) * NDH + 4 * g];

    const int nkA = (len <= q0A) ? 0 : min(q0A + 16, len);
    const int nkB = (len <= q0B) ? 0 : min(q0B + 16, len);
    const int ntA = (nkA + 63) >> 6, ntB = (nkB + 63) >> 6;
    const int ntM = max(ntA, ntB);
    const v4f z4v = {0.f, 0.f, 0.f, 0.f};

    float ZA = 0.f, ZB = 0.f;
    for (int tile = 0; tile < ntM; ++tile) {
        const int ks = (tile << 6) + (kq << 4);
        if (ks >= nkA && ks >= nkB) continue;
        const v4h K = *(const v4h*)&kh[(hbase + ks + n16) * NDH + 4 * g];
        if (ks < nkA) {
            v4f st = __builtin_amdgcn_mfma_f32_16x16x16f16(K, QA, z4v, 0, 0, 0);
            #pragma unroll
            for (int i = 0; i < 4; ++i) {
                int kg = ks + 4 * g + i;
                ZA += (qvA && kg <= qA_) ? __expf(st[i] * 0.125f) : 0.f;
            }
        }
        if (ks < nkB) {
            v4f st = __builtin_amdgcn_mfma_f32_16x16x16f16(K, QB, z4v, 0, 0, 0);
            #pragma unroll
            for (int i = 0; i < 4; ++i) {
                int kg = ks + 4 * g + i;
                ZB += (qvB && kg <= qB_) ? __expf(st[i] * 0.125f) : 0.f;
            }
        }
    }
    ZA += __shfl_xor(ZA, 16, 64); ZA += __shfl_xor(ZA, 32, 64);
    ZB += __shfl_xor(ZB, 16, 64); ZB += __shfl_xor(ZB, 32, 64);
    if (l < 16) {
        zlds[kq][h][n16][0] = ZA;
        zlds[kq][h][n16][1] = ZB;
    }
    __syncthreads();
    const float ztA = zlds[0][h][n16][0] + zlds[1][h][n16][0]
                    + zlds[2][h][n16][0] + zlds[3][h][n16][0];
    const float ztB = zlds[0][h][n16][1] + zlds[1][h][n16][1]
                    + zlds[2][h][n16][1] + zlds[3][h][n16][1];
    const float izA = (ztA > 0.f) ? 1.f / ztA : 0.f;
    const float izB = (ztB > 0.f) ? 1.f / ztB : 0.f;

    v4f oA = z4v, oB = z4v;
    for (int tile = 0; tile < ntM; ++tile) {
        const int k0 = tile << 6;
        const int ks = k0 + (kq << 4);
        const bool doA = tile < ntA, doB = tile < ntB;
        v4f pA = z4v, pB = z4v;
        if (ks < nkA || ks < nkB) {
            const v4h K = *(const v4h*)&kh[(hbase + ks + n16) * NDH + 4 * g];
            const v4h V = *(const v4h*)&vt[(((size_t)(b * NHEADS + h)) * NDH + n16) * NS + ks + 4 * g];
            if (ks < nkA) {
                v4f st = __builtin_amdgcn_mfma_f32_16x16x16f16(K, QA, z4v, 0, 0, 0);
                #pragma unroll
                for (int i = 0; i < 4; ++i) {
                    int kg = ks + 4 * g + i;
                    pA[i] = (qvA && kg <= qA_) ? __expf(st[i] * 0.125f) * izA : 0.f;
                }
                v4h ph = {(_Float16)pA[0], (_Float16)pA[1], (_Float16)pA[2], (_Float16)pA[3]};
                oA = __builtin_amdgcn_mfma_f32_16x16x16f16(ph, V, oA, 0, 0, 0);
            }
            if (ks < nkB) {
                v4f st = __builtin_amdgcn_mfma_f32_16x16x16f16(K, QB, z4v, 0, 0, 0);
                #pragma unroll
                for (int i = 0; i < 4; ++i) {
                    int kg = ks + 4 * g + i;
                    pB[i] = (qvB && kg <= qB_) ? __expf(st[i] * 0.125f) * izB : 0.f;
                }
                v4h ph = {(_Float16)pB[0], (_Float16)pB[1], (_Float16)pB[2], (_Float16)pB[3]};
                oB = __builtin_amdgcn_mfma_f32_16x16x16f16(ph, V, oB, 0, 0, 0);
            }
        }
        const int pc = (kq << 4) + 4 * g;
        *(float4*)&Plds[0][h][n16][pc] =
            make_float4(0.25f * pA[0], 0.25f * pA[1], 0.25f * pA[2], 0.25f * pA[3]);
        *(float4*)&Plds[1][h][n16][pc] =
            make_float4(0.25f * pB[0], 0.25f * pB[1], 0.25f * pB[2], 0.25f * pB[3]);
        __syncthreads();
        if (t < 512) {
            const int sid = t >> 8, r = (t >> 4) & 15, c4 = (t & 15) * 4;
            if (sid == 0 ? doA : doB) {
                float4 a0 = *(float4*)&Plds[sid][0][r][c4];
                float4 a1 = *(float4*)&Plds[sid][1][r][c4];
                float4 a2 = *(float4*)&Plds[sid][2][r][c4];
                float4 a3 = *(float4*)&Plds[sid][3][r][c4];
                float4 wv4 = make_float4(a0.x + a1.x + a2.x + a3.x,
                                         a0.y + a1.y + a2.y + a3.y,
                                         a0.z + a1.z + a2.z + a3.z,
                                         a0.w + a1.w + a2.w + a3.w);
                const int q0 = sid == 0 ? q0A : q0B;
                *(float4*)&amean[((size_t)(b * NS + q0 + r)) * NS + k0 + c4] = wv4;
            }
        }
        __syncthreads();
    }

    float* obuf = (float*)Plds;
    {
        float* p = &obuf[(wv * 64 + l) * 8];
        p[0] = oA[0]; p[1] = oA[1]; p[2] = oA[2]; p[3] = oA[3];
        p[4] = oB[0]; p[5] = oB[1]; p[6] = oB[2]; p[7] = oB[3];
    }
    __syncthreads();
    if (kq == 0) {
        #pragma unroll
        for (int kq2 = 1; kq2 < 4; ++kq2) {
            const float* p = &obuf[(((h + 4 * kq2) * 64) + l) * 8];
            oA[0] += p[0]; oA[1] += p[1]; oA[2] += p[2]; oA[3] += p[3];
            oB[0] += p[4]; oB[1] += p[5]; oB[2] += p[6]; oB[3] += p[7];
        }
        #pragma unroll
        for (int i = 0; i < 4; ++i) {
            out[((size_t)(b * NS) + q0A + 4 * g + i) * NHID + h * 16 + n16] = oA[i];
            out[((size_t)(b * NS) + q0B + 4 * g + i) * NHID + h * 16 + n16] = oB[i];
        }
    }

    const float4 zf = make_float4(0.f, 0.f, 0.f, 0.f);
    {
        const int kzA = ntA << 6;
        const int nzA = (NS - kzA) >> 2;
        for (int r = 0; r < 16; ++r)
            for (int c4 = t; c4 < nzA; c4 += 1024)
                *(float4*)&amean[((size_t)(b * NS + q0A + r)) * NS + kzA + c4 * 4] = zf;
        const int kzB = ntB << 6;
        const int nzB = (NS - kzB) >> 2;
        for (int r = 0; r < 16; ++r)
            for (int c4 = t; c4 < nzB; c4 += 1024)
                *(float4*)&amean[((size_t)(b * NS + q0B + r)) * NS + kzB + c4 * 4] = zf;
    }
}

// ---------------------------------------------------------------------------
// Kernel 3 (ffn_mfma): one wave per 16-row tile; no LDS, no barriers.
// LN1 in fragment layout (lane = row l&15, cols 4g+i per kb; reduce = regs +
// shfl_xor 16,32). GEMM1 computes h1^T = W1.n1^T whose D-fragment is exactly
// GEMM2's B-operand (transposed-product chaining, as attn7). GEMM2 gives
// ff[row][c] back in n1's layout -> residual + LN2 in-register.
// ---------------------------------------------------------------------------
__global__ __launch_bounds__(256) void ffn_mfma_kernel(
    const float* __restrict__ x, const float* __restrict__ aout,
    const float* __restrict__ W1, const float* __restrict__ b1,
    const float* __restrict__ W2, const float* __restrict__ b2,
    const float* __restrict__ g1, const float* __restrict__ be1,
    const float* __restrict__ g2, const float* __restrict__ be2,
    float* __restrict__ y)
{
    const int t = threadIdx.x;
    const int w = t >> 6, l = t & 63;
    const int n16 = l & 15, g = l >> 4;
    const int rt = (int)blockIdx.x * 4 + w;
    const size_t row = (size_t)rt * 16 + n16;

    // o1 = x + aout, fragment layout
    float4 o1f[4];
    #pragma unroll
    for (int kb = 0; kb < 4; ++kb) {
        float4 xv = *(const float4*)&x[row * 64 + kb * 16 + 4 * g];
        float4 av = *(const float4*)&aout[row * 64 + kb * 16 + 4 * g];
        o1f[kb] = make_float4(xv.x + av.x, xv.y + av.y, xv.z + av.z, xv.w + av.w);
    }
    // LN1
    float s = 0.f;
    #pragma unroll
    for (int kb = 0; kb < 4; ++kb) s += o1f[kb].x + o1f[kb].y + o1f[kb].z + o1f[kb].w;
    s += __shfl_xor(s, 16, 64); s += __shfl_xor(s, 32, 64);
    const float mu = s * (1.f / 64.f);
    float vs = 0.f;
    #pragma unroll
    for (int kb = 0; kb < 4; ++kb) {
        float a = o1f[kb].x - mu, bq_ = o1f[kb].y - mu, c = o1f[kb].z - mu, d = o1f[kb].w - mu;
        vs += a * a + bq_ * bq_ + c * c + d * d;
    }
    vs += __shfl_xor(vs, 16, 64); vs += __shfl_xor(vs, 32, 64);
    const float rs = rsqrtf(vs * (1.f / 64.f) + LN_EPS);

    float4 n1v[4]; v4h n1h[4];
    #pragma unroll
    for (int kb = 0; kb < 4; ++kb) {
        float4 gv  = *(const float4*)&g1[kb * 16 + 4 * g];
        float4 bev = *(const float4*)&be1[kb * 16 + 4 * g];
        n1v[kb].x = (o1f[kb].x - mu) * rs * gv.x + bev.x;
        n1v[kb].y = (o1f[kb].y - mu) * rs * gv.y + bev.y;
        n1v[kb].z = (o1f[kb].z - mu) * rs * gv.z + bev.z;
        n1v[kb].w = (o1f[kb].w - mu) * rs * gv.w + bev.w;
        n1h[kb] = cvt4h(n1v[kb]);
    }

    // GEMM1: h1^T = gelu(W1 . n1^T + b1)
    v4h h1h[4];
    #pragma unroll
    for (int db = 0; db < 4; ++db) {
        const float4 b1v = *(const float4*)&b1[db * 16 + 4 * g];
        v4f acc = {b1v.x, b1v.y, b1v.z, b1v.w};
        #pragma unroll
        for (int kb = 0; kb < 4; ++kb) {
            v4h wf = cvt4h(*(const float4*)&W1[(size_t)(db * 16 + n16) * 64 + kb * 16 + 4 * g]);
            acc = __builtin_amdgcn_mfma_f32_16x16x16f16(wf, n1h[kb], acc, 0, 0, 0);
        }
        v4h hh;
        #pragma unroll
        for (int i = 0; i < 4; ++i) {
            float a = acc[i];
            hh[i] = (_Float16)(0.5f * a * (1.f + erff(a * 0.70710678118654752f)));
        }
        h1h[db] = hh;
    }

    // GEMM2: ff^T = W2 . h1^T + b2 ; z = n1 + ff
    float4 zf4[4];
    #pragma unroll
    for (int m2 = 0; m2 < 4; ++m2) {
        const float4 b2v = *(const float4*)&b2[m2 * 16 + 4 * g];
        v4f acc = {b2v.x, b2v.y, b2v.z, b2v.w};
        #pragma unroll
        for (int db = 0; db < 4; ++db) {
            v4h wf = cvt4h(*(const float4*)&W2[(size_t)(m2 * 16 + n16) * 64 + db * 16 + 4 * g]);
            acc = __builtin_amdgcn_mfma_f32_16x16x16f16(wf, h1h[db], acc, 0, 0, 0);
        }
        zf4[m2] = make_float4(n1v[m2].x + acc[0], n1v[m2].y + acc[1],
                              n1v[m2].z + acc[2], n1v[m2].w + acc[3]);
    }

    // LN2
    float s2 = 0.f;
    #pragma unroll
    for (int m2 = 0; m2 < 4; ++m2) s2 += zf4[m2].x + zf4[m2].y + zf4[m2].z + zf4[m2].w;
    s2 += __shfl_xor(s2, 16, 64); s2 += __shfl_xor(s2, 32, 64);
    const float mu2 = s2 * (1.f / 64.f);
    float vs2 = 0.f;
    #pragma unroll
    for (int m2 = 0; m2 < 4; ++m2) {
        float a = zf4[m2].x - mu2, bq_ = zf4[m2].y - mu2, c = zf4[m2].z - mu2, d = zf4[m2].w - mu2;
        vs2 += a * a + bq_ * bq_ + c * c + d * d;
    }
    vs2 += __shfl_xor(vs2, 16, 64); vs2 += __shfl_xor(vs2, 32, 64);
    const float rs2 = rsqrtf(vs2 * (1.f / 64.f) + LN_EPS);
    #pragma unroll
    for (int m2 = 0; m2 < 4; ++m2) {
        float4 gv  = *(const float4*)&g2[m2 * 16 + 4 * g];
        float4 bev = *(const float4*)&be2[m2 * 16 + 4 * g];
        float4 yv;
        yv.x = (zf4[m2].x - mu2) * rs2 * gv.x + bev.x;
        yv.y = (zf4[m2].y - mu2) * rs2 * gv.y + bev.y;
        yv.z = (zf4[m2].z - mu2) * rs2 * gv.z + bev.z;
        yv.w = (zf4[m2].w - mu2) * rs2 * gv.w + bev.w;
        *(float4*)&y[row * 64 + m2 * 16 + 4 * g] = yv;
    }
}

// ---------------------------------------------------------------------------
extern "C" void kernel_launch(void* const* d_in, const int* in_sizes, int n_in,
                              void* d_out, int out_size, void* d_ws, size_t ws_size,
                              hipStream_t stream) {
    const float* x   = (const float*)d_in[0];
    const int* lengths = (const int*)d_in[1];
    const float* Wq  = (const float*)d_in[3];
    const float* bq  = (const float*)d_in[4];
    const float* Wk  = (const float*)d_in[5];
    const float* bk  = (const float*)d_in[6];
    const float* Wv  = (const float*)d_in[7];
    const float* bv  = (const float*)d_in[8];
    const float* W1  = (const float*)d_in[9];
    const float* b1  = (const float*)d_in[10];
    const float* W2  = (const float*)d_in[11];
    const float* b2  = (const float*)d_in[12];
    const float* g1  = (const float*)d_in[13];
    const float* be1 = (const float*)d_in[14];
    const float* g2  = (const float*)d_in[15];
    const float* be2 = (const float*)d_in[16];

    float* y     = (float*)d_out;                       // [B,S,64]
    float* amean = y + (size_t)NB * NS * NHID;          // [B,S,S]

    const size_t nqkv = (size_t)NB * NHEADS * NS * NDH; // 1,048,576 elems
    _Float16* qhw = (_Float16*)d_ws;                    // f16 [B,NH,S,16]
    _Float16* khw = qhw + nqkv;
    _Float16* vtw = khw + nqkv;                         // f16 [B,NH,16,S]
    float* aoutw  = (float*)(vtw + nqkv);               // fp32 [B,S,64]

    hipLaunchKernelGGL(qkv_mfma_kernel, dim3(NB * NS / 64), dim3(256), 0, stream,
                       x, Wq, bq, Wk, bk, Wv, bv, qhw, khw, vtw);
    hipLaunchKernelGGL(attn8_kernel, dim3(32, NB), dim3(1024), 0, stream,
                       qhw, khw, vtw, lengths, amean, aoutw);
    hipLaunchKernelGGL(ffn_mfma_kernel, dim3(NB * NS / 64), dim3(256), 0, stream,
                       x, aoutw, W1, b1, W2, b2, g1, be1, g2, be2, y);
}